// Round 1
// baseline (1289.744 us; speedup 1.0000x reference)
//
#include <hip/hip_runtime.h>

// ---------------- helpers ----------------
typedef __attribute__((ext_vector_type(8))) short bf16x8;   // 8 bf16 (4 VGPRs)
typedef __attribute__((ext_vector_type(4))) float f32x4;

#define DEV static __device__ __forceinline__

DEV float b2f(unsigned short u) {
    union { unsigned int u; float f; } c; c.u = ((unsigned int)u) << 16; return c.f;
}
DEV unsigned short f2b(float f) {
    union { float f; unsigned int u; } c; c.f = f;
    unsigned int u = c.u + 0x7fffu + ((c.u >> 16) & 1u);
    return (unsigned short)(u >> 16);
}
DEV float silu_f(float v) { return v / (1.f + __expf(-v)); }

#define GLD16(gp, lp) __builtin_amdgcn_global_load_lds( \
    (const __attribute__((address_space(1))) void*)(gp), \
    (__attribute__((address_space(3))) void*)(lp), 16, 0, 0)

// sizes
#define LSEQ 2048
#define NB 2
#define RTOT 4096          // NB*LSEQ
#define DM 1024
#define DI 2048
#define NH 32
#define HP 64
#define NSTATE 16
#define CDIM 2080
#define DIP 4160           // per-dir in_proj width
#define NW 8320            // stacked width

// ---------------- f32 -> bf16 convert ----------------
__global__ __launch_bounds__(256) void cvt_kernel(const float* __restrict__ src,
                                                  unsigned short* __restrict__ dst, int n4) {
    int i = blockIdx.x * 256 + threadIdx.x;
    if (i >= n4) return;
    float4 v = ((const float4*)src)[i];
    union { unsigned short s[4]; uint2 u; } p;
    p.s[0] = f2b(v.x); p.s[1] = f2b(v.y); p.s[2] = f2b(v.z); p.s[3] = f2b(v.w);
    ((uint2*)dst)[i] = p.u;
}

// ---------------- bf16 MFMA GEMM, 128x128 tile, B given transposed (N x K) ----------------
// EPI: 1 = store bf16, 2 = out = ex + v*esc[col] (f32)
template<int EPI>
__global__ __launch_bounds__(256, 2) void gemm_kernel(
    const unsigned short* __restrict__ A,     // M x K row-major bf16
    const unsigned short* __restrict__ BT,    // N x K row-major bf16
    void* __restrict__ Cout,
    int M, int N, int K, int ldc, int coff,
    const float* __restrict__ ex, const float* __restrict__ esc)
{
    __shared__ unsigned short lA[128 * 64];
    __shared__ unsigned short lB[128 * 64];
    const int tid  = threadIdx.x;
    const int bm   = blockIdx.y * 128, bn = blockIdx.x * 128;
    const int wave = tid >> 6, lane = tid & 63;
    const int wm   = (wave >> 1) * 64, wn = (wave & 1) * 64;
    const int lr   = lane & 15, lq = lane >> 4;

    f32x4 acc[4][4];
#pragma unroll
    for (int i = 0; i < 4; ++i)
#pragma unroll
        for (int j = 0; j < 4; ++j) acc[i][j] = (f32x4){0.f, 0.f, 0.f, 0.f};

    for (int k0 = 0; k0 < K; k0 += 64) {
#pragma unroll
        for (int i = 0; i < 4; ++i) {
            int c = tid + i * 256;
            int row = c >> 3, col = (c & 7) << 3;
            const unsigned short* ga = A  + (size_t)(bm + row) * K + (k0 + col);
            const unsigned short* gb = BT + (size_t)(bn + row) * K + (k0 + col);
            unsigned short* la = &lA[(i * 256 + (tid & ~63)) * 8];
            unsigned short* lb = &lB[(i * 256 + (tid & ~63)) * 8];
            GLD16(ga, la);
            GLD16(gb, lb);
        }
        __syncthreads();
#pragma unroll
        for (int kk = 0; kk < 64; kk += 32) {
            bf16x8 af[4], bf[4];
#pragma unroll
            for (int mi = 0; mi < 4; ++mi)
                af[mi] = *(const bf16x8*)&lA[(wm + mi * 16 + lr) * 64 + kk + lq * 8];
#pragma unroll
            for (int ni = 0; ni < 4; ++ni)
                bf[ni] = *(const bf16x8*)&lB[(wn + ni * 16 + lr) * 64 + kk + lq * 8];
#pragma unroll
            for (int mi = 0; mi < 4; ++mi)
#pragma unroll
                for (int ni = 0; ni < 4; ++ni)
                    acc[mi][ni] = __builtin_amdgcn_mfma_f32_16x16x32_bf16(af[mi], bf[ni], acc[mi][ni], 0, 0, 0);
        }
        __syncthreads();
    }

#pragma unroll
    for (int mi = 0; mi < 4; ++mi)
#pragma unroll
        for (int ni = 0; ni < 4; ++ni)
#pragma unroll
            for (int r = 0; r < 4; ++r) {
                int grow = bm + wm + mi * 16 + lq * 4 + r;
                int gcol = bn + wn + ni * 16 + lr;
                float v = acc[mi][ni][r];
                if (EPI == 1) {
                    ((unsigned short*)Cout)[(size_t)grow * ldc + coff + gcol] = f2b(v);
                } else {
                    size_t idx = (size_t)grow * ldc + gcol;
                    ((float*)Cout)[idx] = ex[idx] + v * esc[gcol];
                }
            }
}

// ---------------- depthwise causal/anticausal conv + silu + split ----------------
__global__ __launch_bounds__(256) void conv_kernel(
    const unsigned short* __restrict__ ZX,   // [4096][8320] bf16
    const float* __restrict__ cwF, const float* __restrict__ cbF,
    const float* __restrict__ cwB, const float* __restrict__ cbB,
    unsigned short* __restrict__ xs,         // [2][4096][2048] bf16
    float* __restrict__ Bc, float* __restrict__ Cc)  // [(d*2+b)*L+t][16]
{
    const int c = blockIdx.x * 256 + threadIdx.x;
    if (c >= CDIM) return;
    const int t  = blockIdx.y;
    const int db = blockIdx.z;
    const int d = db >> 1, b = db & 1;
    const float* cw = d ? cwB : cwF;
    const float* cb = d ? cbB : cbF;
    float4 w = *(const float4*)&cw[c * 4];
    float acc = cb[c];
    const unsigned short* base = ZX + (size_t)d * DIP + DI + c;  // + row*8320
    if (d == 0) {
        int tj;
        tj = t - 3; if (tj >= 0) acc += w.x * b2f(base[(size_t)(b * LSEQ + tj) * NW]);
        tj = t - 2; if (tj >= 0) acc += w.y * b2f(base[(size_t)(b * LSEQ + tj) * NW]);
        tj = t - 1; if (tj >= 0) acc += w.z * b2f(base[(size_t)(b * LSEQ + tj) * NW]);
        acc += w.w * b2f(base[(size_t)(b * LSEQ + t) * NW]);
    } else {
        int tj;
        tj = t + 3; if (tj < LSEQ) acc += w.x * b2f(base[(size_t)(b * LSEQ + tj) * NW]);
        tj = t + 2; if (tj < LSEQ) acc += w.y * b2f(base[(size_t)(b * LSEQ + tj) * NW]);
        tj = t + 1; if (tj < LSEQ) acc += w.z * b2f(base[(size_t)(b * LSEQ + tj) * NW]);
        acc += w.w * b2f(base[(size_t)(b * LSEQ + t) * NW]);
    }
    float v = silu_f(acc);
    const int row = b * LSEQ + t;
    if (c < DI) {
        xs[((size_t)d * RTOT + row) * DI + c] = f2b(v);
    } else if (c < DI + NSTATE) {
        Bc[((size_t)(d * 2 + b) * LSEQ + t) * NSTATE + (c - DI)] = v;
    } else {
        Cc[((size_t)(d * 2 + b) * LSEQ + t) * NSTATE + (c - DI - NSTATE)] = v;
    }
}

// ---------------- dt: softplus + dA ----------------
__global__ __launch_bounds__(256) void dt_kernel(
    const unsigned short* __restrict__ ZX,
    const float* __restrict__ biasF, const float* __restrict__ AlogF,
    const float* __restrict__ biasB, const float* __restrict__ AlogB,
    float* __restrict__ dtb, float* __restrict__ dAb)
{
    int i = blockIdx.x * 256 + threadIdx.x;          // [d][b][t][h]
    int h = i & 31, t = (i >> 5) & 2047, b = (i >> 16) & 1, d = (i >> 17) & 1;
    float raw = b2f(ZX[(size_t)(b * LSEQ + t) * NW + d * DIP + (DI + CDIM) + h]);
    float bias = (d ? biasB : biasF)[h];
    float Alog = (d ? AlogB : AlogF)[h];
    float xv = raw + bias;
    float dt = (xv > 20.f) ? xv : __logf(1.f + __expf(xv));
    float A = -__expf(Alog);
    dtb[i] = dt;
    dAb[i] = __expf(dt * A);
}

#define LD16V(dst, ptr) do { const float4* _p = (const float4*)(ptr); \
    float4 _q0 = _p[0], _q1 = _p[1], _q2 = _p[2], _q3 = _p[3]; \
    dst[0]=_q0.x; dst[1]=_q0.y; dst[2]=_q0.z; dst[3]=_q0.w; \
    dst[4]=_q1.x; dst[5]=_q1.y; dst[6]=_q1.z; dst[7]=_q1.w; \
    dst[8]=_q2.x; dst[9]=_q2.y; dst[10]=_q2.z; dst[11]=_q2.w; \
    dst[12]=_q3.x; dst[13]=_q3.y; dst[14]=_q3.z; dst[15]=_q3.w; } while (0)

// ---------------- sequential SSM scan, one wave per (b,dir,head) ----------------
__global__ __launch_bounds__(64) void scan_kernel(
    const unsigned short* __restrict__ xs,   // [2][4096][2048]
    const float* __restrict__ Bc, const float* __restrict__ Cc,
    const float* __restrict__ dtb, const float* __restrict__ dAb,
    const float* __restrict__ DpF, const float* __restrict__ DpB,
    unsigned short* __restrict__ ybuf)       // [2][4096][2048]
{
    const int h = blockIdx.x, b = blockIdx.y, d = blockIdx.z;
    const int lane = threadIdx.x;
    const float Dp = (d ? DpB : DpF)[h];
    float hs[16];
#pragma unroll
    for (int n = 0; n < 16; ++n) hs[n] = 0.f;

    const size_t dbase = (size_t)d * RTOT;
    float Bs[16], Cs[16], xv, dtv, dAv;
    float Bn[16], Cn[16], xn, dtn, dAn;
    {
        const int t = d ? (LSEQ - 1) : 0;
        const size_t row = (size_t)b * LSEQ + t, rdb = (size_t)(d * 2 + b) * LSEQ + t;
        xv  = b2f(xs[(dbase + row) * DI + h * HP + lane]);
        dtv = dtb[rdb * 32 + h]; dAv = dAb[rdb * 32 + h];
        LD16V(Bs, Bc + rdb * 16);
        LD16V(Cs, Cc + rdb * 16);
    }
#pragma unroll 2
    for (int s = 0; s < LSEQ; ++s) {
        const int sn = (s < LSEQ - 1) ? s + 1 : s;
        const int tn = d ? (LSEQ - 1 - sn) : sn;
        {   // prefetch next step
            const size_t rown = (size_t)b * LSEQ + tn, rdbn = (size_t)(d * 2 + b) * LSEQ + tn;
            xn  = b2f(xs[(dbase + rown) * DI + h * HP + lane]);
            dtn = dtb[rdbn * 32 + h]; dAn = dAb[rdbn * 32 + h];
            LD16V(Bn, Bc + rdbn * 16);
            LD16V(Cn, Cc + rdbn * 16);
        }
        const float dtx = dtv * xv;
        float yq[4] = {0.f, 0.f, 0.f, 0.f};
#pragma unroll
        for (int n = 0; n < 16; ++n) {
            hs[n] = fmaf(hs[n], dAv, Bs[n] * dtx);
            yq[n & 3] = fmaf(Cs[n], hs[n], yq[n & 3]);
        }
        const int t = d ? (LSEQ - 1 - s) : s;
        const size_t row = (size_t)b * LSEQ + t;
        ybuf[(dbase + row) * DI + h * HP + lane] = f2b(((yq[0] + yq[1]) + (yq[2] + yq[3])) + Dp * xv);

        xv = xn; dtv = dtn; dAv = dAn;
#pragma unroll
        for (int n = 0; n < 16; ++n) { Bs[n] = Bn[n]; Cs[n] = Cn[n]; }
    }
}

// ---------------- gate (silu(z)) + RMSNorm -> bf16 ----------------
__global__ __launch_bounds__(256) void gatenorm_kernel(
    const unsigned short* __restrict__ ybuf, const unsigned short* __restrict__ ZX,
    const float* __restrict__ nwF, const float* __restrict__ nwB,
    unsigned short* __restrict__ yg)
{
    const int r = blockIdx.x;      // 0..4095 (b*L+t)
    const int d = blockIdx.y;
    const int tid = threadIdx.x;
    const float* nw = d ? nwB : nwF;
    const int c0 = tid * 8;
    const unsigned short* yp = ybuf + ((size_t)d * RTOT + r) * DI + c0;
    const unsigned short* zp = ZX + (size_t)r * NW + d * DIP + c0;
    uint4 yv = *(const uint4*)yp;
    uint4 zv = *(const uint4*)zp;
    unsigned int yw[4] = {yv.x, yv.y, yv.z, yv.w};
    unsigned int zw[4] = {zv.x, zv.y, zv.z, zv.w};
    float g[8]; float ss = 0.f;
#pragma unroll
    for (int i = 0; i < 8; ++i) {
        unsigned short yu = (i & 1) ? (unsigned short)(yw[i >> 1] >> 16) : (unsigned short)(yw[i >> 1] & 0xffff);
        unsigned short zu = (i & 1) ? (unsigned short)(zw[i >> 1] >> 16) : (unsigned short)(zw[i >> 1] & 0xffff);
        float y = b2f(yu), z = b2f(zu);
        float gv = y * silu_f(z);
        g[i] = gv; ss += gv * gv;
    }
#pragma unroll
    for (int m = 1; m < 64; m <<= 1) ss += __shfl_xor(ss, m, 64);
    __shared__ float red[4];
    if ((tid & 63) == 0) red[tid >> 6] = ss;
    __syncthreads();
    float tot = red[0] + red[1] + red[2] + red[3];
    float sc = rsqrtf(tot * (1.f / 2048.f) + 1e-5f);
    union { unsigned short s[8]; uint4 u; } o;
#pragma unroll
    for (int i = 0; i < 8; ++i) o.s[i] = f2b(g[i] * sc * nw[c0 + i]);
    *(uint4*)(yg + ((size_t)d * RTOT + r) * DI + c0) = o.u;
}

// ---------------- host ----------------
extern "C" void kernel_launch(void* const* d_in, const int* in_sizes, int n_in,
                              void* d_out, int out_size, void* d_ws, size_t ws_size,
                              hipStream_t stream)
{
    const float* x     = (const float*)d_in[0];
    const float* fin   = (const float*)d_in[1];
    const float* fcw   = (const float*)d_in[2];
    const float* fcb   = (const float*)d_in[3];
    const float* fdtb  = (const float*)d_in[4];
    const float* fAlog = (const float*)d_in[5];
    const float* fDp   = (const float*)d_in[6];
    const float* fnw   = (const float*)d_in[7];
    const float* fout  = (const float*)d_in[8];
    const float* bin   = (const float*)d_in[9];
    const float* bcw   = (const float*)d_in[10];
    const float* bcb   = (const float*)d_in[11];
    const float* bdtb  = (const float*)d_in[12];
    const float* bAlog = (const float*)d_in[13];
    const float* bDp   = (const float*)d_in[14];
    const float* bnw   = (const float*)d_in[15];
    const float* bout  = (const float*)d_in[16];
    const float* lw    = (const float*)d_in[17];
    const float* lsc   = (const float*)d_in[18];

    char* w = (char*)d_ws;
    auto alloc = [&](size_t bytes) { char* p = w; w += (bytes + 255) & ~(size_t)255; return p; };
    unsigned short* xb  = (unsigned short*)alloc((size_t)RTOT * DM * 2);        // 8.4 MB
    unsigned short* win = (unsigned short*)alloc((size_t)NW * DM * 2);          // 17 MB
    unsigned short* wo  = (unsigned short*)alloc((size_t)2 * DM * DI * 2);      // 8.4 MB
    unsigned short* wl  = (unsigned short*)alloc((size_t)DM * DI * 2);          // 4.2 MB
    unsigned short* zx  = (unsigned short*)alloc((size_t)RTOT * NW * 2);        // 68 MB
    unsigned short* xs  = (unsigned short*)alloc((size_t)2 * RTOT * DI * 2);    // 33.5 MB
    float* Bc  = (float*)alloc((size_t)2 * RTOT * NSTATE * 4);
    float* Cc  = (float*)alloc((size_t)2 * RTOT * NSTATE * 4);
    float* dtb = (float*)alloc((size_t)2 * RTOT * NH * 4);
    float* dAb = (float*)alloc((size_t)2 * RTOT * NH * 4);
    unsigned short* yb  = (unsigned short*)alloc((size_t)2 * RTOT * DI * 2);    // 33.5 MB
    unsigned short* yg  = (unsigned short*)alloc((size_t)2 * RTOT * DI * 2);    // 33.5 MB
    unsigned short* hbi = (unsigned short*)alloc((size_t)RTOT * DI * 2);        // 16.8 MB
    (void)ws_size; (void)in_sizes; (void)n_in; (void)out_size;  // total ~227 MB

    // weight / activation converts to bf16
    cvt_kernel<<<RTOT * DM / 1024, 256, 0, stream>>>(x, xb, RTOT * DM / 4);
    cvt_kernel<<<DIP * DM / 1024, 256, 0, stream>>>(fin, win, DIP * DM / 4);
    cvt_kernel<<<DIP * DM / 1024, 256, 0, stream>>>(bin, win + (size_t)DIP * DM, DIP * DM / 4);
    cvt_kernel<<<DM * DI / 1024, 256, 0, stream>>>(fout, wo, DM * DI / 4);
    cvt_kernel<<<DM * DI / 1024, 256, 0, stream>>>(bout, wo + (size_t)DM * DI, DM * DI / 4);
    cvt_kernel<<<DM * DI / 1024, 256, 0, stream>>>(lw, wl, DM * DI / 4);

    // GEMM A: zxbcdt for both dirs (stacked weights)
    gemm_kernel<1><<<dim3(NW / 128, RTOT / 128), 256, 0, stream>>>(
        xb, win, zx, RTOT, NW, DM, NW, 0, nullptr, nullptr);

    // conv + silu + split (fwd causal, bwd anti-causal)
    conv_kernel<<<dim3((CDIM + 255) / 256, LSEQ, 4), 256, 0, stream>>>(
        zx, fcw, fcb, bcw, bcb, xs, Bc, Cc);

    // dt softplus + dA
    dt_kernel<<<(2 * NB * LSEQ * NH) / 256, 256, 0, stream>>>(
        zx, fdtb, fAlog, bdtb, bAlog, dtb, dAb);

    // sequential scan (fwd: t=0..L-1, bwd: t=L-1..0)
    scan_kernel<<<dim3(NH, NB, 2), 64, 0, stream>>>(xs, Bc, Cc, dtb, dAb, fDp, bDp, yb);

    // gate + RMSNorm
    gatenorm_kernel<<<dim3(RTOT, 2), 256, 0, stream>>>(yb, zx, fnw, bnw, yg);

    // GEMM B: out_proj per dir -> hbi (concat along cols)
    gemm_kernel<1><<<dim3(DM / 128, RTOT / 128), 256, 0, stream>>>(
        yg, wo, hbi, RTOT, DM, DI, DI, 0, nullptr, nullptr);
    gemm_kernel<1><<<dim3(DM / 128, RTOT / 128), 256, 0, stream>>>(
        yg + (size_t)RTOT * DI, wo + (size_t)DM * DI, hbi, RTOT, DM, DI, DI, DM, nullptr, nullptr);

    // GEMM C: layer out proj + residual epilogue
    gemm_kernel<2><<<dim3(DM / 128, RTOT / 128), 256, 0, stream>>>(
        hbi, wl, d_out, RTOT, DM, DI, DM, 0, x, lsc);
}

// Round 2
// 483.046 us; speedup vs baseline: 2.6700x; 2.6700x over previous
//
#include <hip/hip_runtime.h>

// ---------------- helpers ----------------
typedef __attribute__((ext_vector_type(8))) short bf16x8;   // 8 bf16 (4 VGPRs)
typedef __attribute__((ext_vector_type(4))) float f32x4;

#define DEV static __device__ __forceinline__

DEV float b2f(unsigned short u) {
    union { unsigned int u; float f; } c; c.u = ((unsigned int)u) << 16; return c.f;
}
DEV unsigned short f2b(float f) {
    union { float f; unsigned int u; } c; c.f = f;
    unsigned int u = c.u + 0x7fffu + ((c.u >> 16) & 1u);
    return (unsigned short)(u >> 16);
}
DEV float silu_f(float v) { return v / (1.f + __expf(-v)); }

#define GLD16(gp, lp) __builtin_amdgcn_global_load_lds( \
    (const __attribute__((address_space(1))) void*)(gp), \
    (__attribute__((address_space(3))) void*)(lp), 16, 0, 0)

// sizes
#define LSEQ 2048
#define NB 2
#define RTOT 4096          // NB*LSEQ
#define DM 1024
#define DI 2048
#define NH 32
#define HP 64
#define NSTATE 16
#define CDIM 2080
#define DIP 4160           // per-dir in_proj width
#define NW 8320            // stacked width
#define QCH 128            // scan chunk length
#define NCH (LSEQ / QCH)   // 16 chunks

// ---------------- f32 -> bf16 convert ----------------
__global__ __launch_bounds__(256) void cvt_kernel(const float* __restrict__ src,
                                                  unsigned short* __restrict__ dst, int n4) {
    int i = blockIdx.x * 256 + threadIdx.x;
    if (i >= n4) return;
    float4 v = ((const float4*)src)[i];
    union { unsigned short s[4]; uint2 u; } p;
    p.s[0] = f2b(v.x); p.s[1] = f2b(v.y); p.s[2] = f2b(v.z); p.s[3] = f2b(v.w);
    ((uint2*)dst)[i] = p.u;
}

// ---------------- bf16 MFMA GEMM, 128x128 tile, B given transposed (N x K) ----------------
// EPI: 1 = store bf16, 2 = out = ex + v*esc[col] (f32)
template<int EPI>
__global__ __launch_bounds__(256, 2) void gemm_kernel(
    const unsigned short* __restrict__ A,     // M x K row-major bf16
    const unsigned short* __restrict__ BT,    // N x K row-major bf16
    void* __restrict__ Cout,
    int M, int N, int K, int ldc, int coff,
    const float* __restrict__ ex, const float* __restrict__ esc)
{
    __shared__ unsigned short lA[128 * 64];
    __shared__ unsigned short lB[128 * 64];
    const int tid  = threadIdx.x;
    const int bm   = blockIdx.y * 128, bn = blockIdx.x * 128;
    const int wave = tid >> 6, lane = tid & 63;
    const int wm   = (wave >> 1) * 64, wn = (wave & 1) * 64;
    const int lr   = lane & 15, lq = lane >> 4;

    f32x4 acc[4][4];
#pragma unroll
    for (int i = 0; i < 4; ++i)
#pragma unroll
        for (int j = 0; j < 4; ++j) acc[i][j] = (f32x4){0.f, 0.f, 0.f, 0.f};

    for (int k0 = 0; k0 < K; k0 += 64) {
#pragma unroll
        for (int i = 0; i < 4; ++i) {
            int c = tid + i * 256;
            int row = c >> 3, col = (c & 7) << 3;
            const unsigned short* ga = A  + (size_t)(bm + row) * K + (k0 + col);
            const unsigned short* gb = BT + (size_t)(bn + row) * K + (k0 + col);
            unsigned short* la = &lA[(i * 256 + (tid & ~63)) * 8];
            unsigned short* lb = &lB[(i * 256 + (tid & ~63)) * 8];
            GLD16(ga, la);
            GLD16(gb, lb);
        }
        __syncthreads();
#pragma unroll
        for (int kk = 0; kk < 64; kk += 32) {
            bf16x8 af[4], bf[4];
#pragma unroll
            for (int mi = 0; mi < 4; ++mi)
                af[mi] = *(const bf16x8*)&lA[(wm + mi * 16 + lr) * 64 + kk + lq * 8];
#pragma unroll
            for (int ni = 0; ni < 4; ++ni)
                bf[ni] = *(const bf16x8*)&lB[(wn + ni * 16 + lr) * 64 + kk + lq * 8];
#pragma unroll
            for (int mi = 0; mi < 4; ++mi)
#pragma unroll
                for (int ni = 0; ni < 4; ++ni)
                    acc[mi][ni] = __builtin_amdgcn_mfma_f32_16x16x32_bf16(af[mi], bf[ni], acc[mi][ni], 0, 0, 0);
        }
        __syncthreads();
    }

#pragma unroll
    for (int mi = 0; mi < 4; ++mi)
#pragma unroll
        for (int ni = 0; ni < 4; ++ni)
#pragma unroll
            for (int r = 0; r < 4; ++r) {
                int grow = bm + wm + mi * 16 + lq * 4 + r;
                int gcol = bn + wn + ni * 16 + lr;
                float v = acc[mi][ni][r];
                if (EPI == 1) {
                    ((unsigned short*)Cout)[(size_t)grow * ldc + coff + gcol] = f2b(v);
                } else {
                    size_t idx = (size_t)grow * ldc + gcol;
                    ((float*)Cout)[idx] = ex[idx] + v * esc[gcol];
                }
            }
}

// ---------------- depthwise causal/anticausal conv + silu + split ----------------
__global__ __launch_bounds__(256) void conv_kernel(
    const unsigned short* __restrict__ ZX,   // [4096][8320] bf16
    const float* __restrict__ cwF, const float* __restrict__ cbF,
    const float* __restrict__ cwB, const float* __restrict__ cbB,
    unsigned short* __restrict__ xs,         // [2][4096][2048] bf16
    float* __restrict__ Bc, float* __restrict__ Cc)  // [(d*2+b)*L+t][16]
{
    const int c = blockIdx.x * 256 + threadIdx.x;
    if (c >= CDIM) return;
    const int t  = blockIdx.y;
    const int db = blockIdx.z;
    const int d = db >> 1, b = db & 1;
    const float* cw = d ? cwB : cwF;
    const float* cb = d ? cbB : cbF;
    float4 w = *(const float4*)&cw[c * 4];
    float acc = cb[c];
    const unsigned short* base = ZX + (size_t)d * DIP + DI + c;  // + row*8320
    if (d == 0) {
        int tj;
        tj = t - 3; if (tj >= 0) acc += w.x * b2f(base[(size_t)(b * LSEQ + tj) * NW]);
        tj = t - 2; if (tj >= 0) acc += w.y * b2f(base[(size_t)(b * LSEQ + tj) * NW]);
        tj = t - 1; if (tj >= 0) acc += w.z * b2f(base[(size_t)(b * LSEQ + tj) * NW]);
        acc += w.w * b2f(base[(size_t)(b * LSEQ + t) * NW]);
    } else {
        int tj;
        tj = t + 3; if (tj < LSEQ) acc += w.x * b2f(base[(size_t)(b * LSEQ + tj) * NW]);
        tj = t + 2; if (tj < LSEQ) acc += w.y * b2f(base[(size_t)(b * LSEQ + tj) * NW]);
        tj = t + 1; if (tj < LSEQ) acc += w.z * b2f(base[(size_t)(b * LSEQ + tj) * NW]);
        acc += w.w * b2f(base[(size_t)(b * LSEQ + t) * NW]);
    }
    float v = silu_f(acc);
    const int row = b * LSEQ + t;
    if (c < DI) {
        xs[((size_t)d * RTOT + row) * DI + c] = f2b(v);
    } else if (c < DI + NSTATE) {
        Bc[((size_t)(d * 2 + b) * LSEQ + t) * NSTATE + (c - DI)] = v;
    } else {
        Cc[((size_t)(d * 2 + b) * LSEQ + t) * NSTATE + (c - DI - NSTATE)] = v;
    }
}

// ---------------- dt: softplus + dA ----------------
__global__ __launch_bounds__(256) void dt_kernel(
    const unsigned short* __restrict__ ZX,
    const float* __restrict__ biasF, const float* __restrict__ AlogF,
    const float* __restrict__ biasB, const float* __restrict__ AlogB,
    float* __restrict__ dtb, float* __restrict__ dAb)
{
    int i = blockIdx.x * 256 + threadIdx.x;          // [d][b][t][h]
    int h = i & 31, t = (i >> 5) & 2047, b = (i >> 16) & 1, d = (i >> 17) & 1;
    float raw = b2f(ZX[(size_t)(b * LSEQ + t) * NW + d * DIP + (DI + CDIM) + h]);
    float bias = (d ? biasB : biasF)[h];
    float Alog = (d ? AlogB : AlogF)[h];
    float xv = raw + bias;
    float dt = (xv > 20.f) ? xv : __logf(1.f + __expf(xv));
    float A = -__expf(Alog);
    dtb[i] = dt;
    dAb[i] = __expf(dt * A);
}

#define LD16V(dst, ptr) do { const float4* _p = (const float4*)(ptr); \
    float4 _q0 = _p[0], _q1 = _p[1], _q2 = _p[2], _q3 = _p[3]; \
    dst[0]=_q0.x; dst[1]=_q0.y; dst[2]=_q0.z; dst[3]=_q0.w; \
    dst[4]=_q1.x; dst[5]=_q1.y; dst[6]=_q1.z; dst[7]=_q1.w; \
    dst[8]=_q2.x; dst[9]=_q2.y; dst[10]=_q2.z; dst[11]=_q2.w; \
    dst[12]=_q3.x; dst[13]=_q3.y; dst[14]=_q3.z; dst[15]=_q3.w; } while (0)

#define ST16V(ptr, src) do { float4* _p = (float4*)(ptr); \
    _p[0] = make_float4(src[0],src[1],src[2],src[3]); \
    _p[1] = make_float4(src[4],src[5],src[6],src[7]); \
    _p[2] = make_float4(src[8],src[9],src[10],src[11]); \
    _p[3] = make_float4(src[12],src[13],src[14],src[15]); } while (0)

// ---------------- pass A: per-chunk zero-init state + decay product ----------------
// grid (NH, 4, NCH-1), 64 threads. lane = p index.
__global__ __launch_bounds__(64) void chunk_state_kernel(
    const unsigned short* __restrict__ xs,   // [2][4096][2048]
    const float* __restrict__ Bc,
    const float* __restrict__ dtb, const float* __restrict__ dAb,
    float* __restrict__ Sbuf,               // [128][NCH][64][16]
    float* __restrict__ Pbuf)               // [128][NCH]
{
    const int h = blockIdx.x, db = blockIdx.y, c = blockIdx.z;
    const int d = db >> 1, b = db & 1;
    const int lane = threadIdx.x;
    float hs[16];
#pragma unroll
    for (int n = 0; n < 16; ++n) hs[n] = 0.f;
    float pacc = 1.f;
    const size_t dbase = (size_t)d * RTOT;
    const int s0 = c * QCH;

    float Bs[16], xv, dtv, dAv;
    float Bn[16], xn, dtn, dAn;
    {
        const int t = d ? (LSEQ - 1 - s0) : s0;
        const size_t row = (size_t)b * LSEQ + t, rdb = (size_t)db * LSEQ + t;
        xv  = b2f(xs[(dbase + row) * DI + h * HP + lane]);
        dtv = dtb[rdb * 32 + h]; dAv = dAb[rdb * 32 + h];
        LD16V(Bs, Bc + rdb * 16);
    }
#pragma unroll 2
    for (int i = 0; i < QCH; ++i) {
        const int sn = s0 + ((i < QCH - 1) ? i + 1 : i);
        const int tn = d ? (LSEQ - 1 - sn) : sn;
        {
            const size_t rown = (size_t)b * LSEQ + tn, rdbn = (size_t)db * LSEQ + tn;
            xn  = b2f(xs[(dbase + rown) * DI + h * HP + lane]);
            dtn = dtb[rdbn * 32 + h]; dAn = dAb[rdbn * 32 + h];
            LD16V(Bn, Bc + rdbn * 16);
        }
        const float dtx = dtv * xv;
#pragma unroll
        for (int n = 0; n < 16; ++n) hs[n] = fmaf(hs[n], dAv, Bs[n] * dtx);
        pacc *= dAv;
        xv = xn; dtv = dtn; dAv = dAn;
#pragma unroll
        for (int n = 0; n < 16; ++n) Bs[n] = Bn[n];
    }
    float* Sp = Sbuf + (((size_t)(db * NH + h)) * NCH + c) * 1024 + lane * 16;
    ST16V(Sp, hs);
    if (lane == 0) Pbuf[(db * NH + h) * NCH + c] = pacc;
}

// ---------------- pass B: sequential combine over chunks (tiny) ----------------
// grid 128 blocks x 64 threads; block = (db*NH+h)
__global__ __launch_bounds__(64) void chunk_combine_kernel(
    const float* __restrict__ Sbuf, const float* __restrict__ Pbuf,
    float* __restrict__ Hbuf)               // [128][NCH][64][16]
{
    const int idx = blockIdx.x;
    const int lane = threadIdx.x;
    float hs[16];
#pragma unroll
    for (int n = 0; n < 16; ++n) hs[n] = 0.f;
    float* H0 = Hbuf + ((size_t)idx * NCH) * 1024 + lane * 16;
    ST16V(H0, hs);
    for (int c = 0; c < NCH - 1; ++c) {
        const float* Sp = Sbuf + ((size_t)idx * NCH + c) * 1024 + lane * 16;
        float S[16];
        LD16V(S, Sp);
        const float P = Pbuf[idx * NCH + c];
#pragma unroll
        for (int n = 0; n < 16; ++n) hs[n] = fmaf(hs[n], P, S[n]);
        float* Hp = Hbuf + ((size_t)idx * NCH + c + 1) * 1024 + lane * 16;
        ST16V(Hp, hs);
    }
}

// ---------------- pass C: per-chunk scan from Hinit, emit y ----------------
// grid (NH, 4, NCH), 64 threads
__global__ __launch_bounds__(64) void chunk_scan_kernel(
    const unsigned short* __restrict__ xs,
    const float* __restrict__ Bc, const float* __restrict__ Cc,
    const float* __restrict__ dtb, const float* __restrict__ dAb,
    const float* __restrict__ DpF, const float* __restrict__ DpB,
    const float* __restrict__ Hbuf,
    unsigned short* __restrict__ ybuf)       // [2][4096][2048]
{
    const int h = blockIdx.x, db = blockIdx.y, c = blockIdx.z;
    const int d = db >> 1, b = db & 1;
    const int lane = threadIdx.x;
    const float Dp = (d ? DpB : DpF)[h];
    float hs[16];
    {
        const float* Hp = Hbuf + ((size_t)(db * NH + h) * NCH + c) * 1024 + lane * 16;
        LD16V(hs, Hp);
    }
    const size_t dbase = (size_t)d * RTOT;
    const int s0 = c * QCH;

    float Bs[16], Cs[16], xv, dtv, dAv;
    float Bn[16], Cn[16], xn, dtn, dAn;
    {
        const int t = d ? (LSEQ - 1 - s0) : s0;
        const size_t row = (size_t)b * LSEQ + t, rdb = (size_t)db * LSEQ + t;
        xv  = b2f(xs[(dbase + row) * DI + h * HP + lane]);
        dtv = dtb[rdb * 32 + h]; dAv = dAb[rdb * 32 + h];
        LD16V(Bs, Bc + rdb * 16);
        LD16V(Cs, Cc + rdb * 16);
    }
#pragma unroll 2
    for (int i = 0; i < QCH; ++i) {
        const int sn = s0 + ((i < QCH - 1) ? i + 1 : i);
        const int tn = d ? (LSEQ - 1 - sn) : sn;
        {
            const size_t rown = (size_t)b * LSEQ + tn, rdbn = (size_t)db * LSEQ + tn;
            xn  = b2f(xs[(dbase + rown) * DI + h * HP + lane]);
            dtn = dtb[rdbn * 32 + h]; dAn = dAb[rdbn * 32 + h];
            LD16V(Bn, Bc + rdbn * 16);
            LD16V(Cn, Cc + rdbn * 16);
        }
        const float dtx = dtv * xv;
        float yq[4] = {0.f, 0.f, 0.f, 0.f};
#pragma unroll
        for (int n = 0; n < 16; ++n) {
            hs[n] = fmaf(hs[n], dAv, Bs[n] * dtx);
            yq[n & 3] = fmaf(Cs[n], hs[n], yq[n & 3]);
        }
        const int t = d ? (LSEQ - 1 - (s0 + i)) : (s0 + i);
        const size_t row = (size_t)b * LSEQ + t;
        ybuf[(dbase + row) * DI + h * HP + lane] = f2b(((yq[0] + yq[1]) + (yq[2] + yq[3])) + Dp * xv);

        xv = xn; dtv = dtn; dAv = dAn;
#pragma unroll
        for (int n = 0; n < 16; ++n) { Bs[n] = Bn[n]; Cs[n] = Cn[n]; }
    }
}

// ---------------- gate (silu(z)) + RMSNorm -> bf16 ----------------
__global__ __launch_bounds__(256) void gatenorm_kernel(
    const unsigned short* __restrict__ ybuf, const unsigned short* __restrict__ ZX,
    const float* __restrict__ nwF, const float* __restrict__ nwB,
    unsigned short* __restrict__ yg)
{
    const int r = blockIdx.x;      // 0..4095 (b*L+t)
    const int d = blockIdx.y;
    const int tid = threadIdx.x;
    const float* nw = d ? nwB : nwF;
    const int c0 = tid * 8;
    const unsigned short* yp = ybuf + ((size_t)d * RTOT + r) * DI + c0;
    const unsigned short* zp = ZX + (size_t)r * NW + d * DIP + c0;
    uint4 yv = *(const uint4*)yp;
    uint4 zv = *(const uint4*)zp;
    unsigned int yw[4] = {yv.x, yv.y, yv.z, yv.w};
    unsigned int zw[4] = {zv.x, zv.y, zv.z, zv.w};
    float g[8]; float ss = 0.f;
#pragma unroll
    for (int i = 0; i < 8; ++i) {
        unsigned short yu = (i & 1) ? (unsigned short)(yw[i >> 1] >> 16) : (unsigned short)(yw[i >> 1] & 0xffff);
        unsigned short zu = (i & 1) ? (unsigned short)(zw[i >> 1] >> 16) : (unsigned short)(zw[i >> 1] & 0xffff);
        float y = b2f(yu), z = b2f(zu);
        float gv = y * silu_f(z);
        g[i] = gv; ss += gv * gv;
    }
#pragma unroll
    for (int m = 1; m < 64; m <<= 1) ss += __shfl_xor(ss, m, 64);
    __shared__ float red[4];
    if ((tid & 63) == 0) red[tid >> 6] = ss;
    __syncthreads();
    float tot = red[0] + red[1] + red[2] + red[3];
    float sc = rsqrtf(tot * (1.f / 2048.f) + 1e-5f);
    union { unsigned short s[8]; uint4 u; } o;
#pragma unroll
    for (int i = 0; i < 8; ++i) o.s[i] = f2b(g[i] * sc * nw[c0 + i]);
    *(uint4*)(yg + ((size_t)d * RTOT + r) * DI + c0) = o.u;
}

// ---------------- host ----------------
extern "C" void kernel_launch(void* const* d_in, const int* in_sizes, int n_in,
                              void* d_out, int out_size, void* d_ws, size_t ws_size,
                              hipStream_t stream)
{
    const float* x     = (const float*)d_in[0];
    const float* fin   = (const float*)d_in[1];
    const float* fcw   = (const float*)d_in[2];
    const float* fcb   = (const float*)d_in[3];
    const float* fdtb  = (const float*)d_in[4];
    const float* fAlog = (const float*)d_in[5];
    const float* fDp   = (const float*)d_in[6];
    const float* fnw   = (const float*)d_in[7];
    const float* fout  = (const float*)d_in[8];
    const float* bin   = (const float*)d_in[9];
    const float* bcw   = (const float*)d_in[10];
    const float* bcb   = (const float*)d_in[11];
    const float* bdtb  = (const float*)d_in[12];
    const float* bAlog = (const float*)d_in[13];
    const float* bDp   = (const float*)d_in[14];
    const float* bnw   = (const float*)d_in[15];
    const float* bout  = (const float*)d_in[16];
    const float* lw    = (const float*)d_in[17];
    const float* lsc   = (const float*)d_in[18];

    char* w = (char*)d_ws;
    auto alloc = [&](size_t bytes) { char* p = w; w += (bytes + 255) & ~(size_t)255; return p; };
    unsigned short* xb  = (unsigned short*)alloc((size_t)RTOT * DM * 2);        // 8.4 MB
    unsigned short* win = (unsigned short*)alloc((size_t)NW * DM * 2);          // 17 MB
    unsigned short* wo  = (unsigned short*)alloc((size_t)2 * DM * DI * 2);      // 8.4 MB
    unsigned short* wl  = (unsigned short*)alloc((size_t)DM * DI * 2);          // 4.2 MB
    unsigned short* zx  = (unsigned short*)alloc((size_t)RTOT * NW * 2);        // 68 MB
    unsigned short* xs  = (unsigned short*)alloc((size_t)2 * RTOT * DI * 2);    // 33.5 MB
    float* Bc  = (float*)alloc((size_t)2 * RTOT * NSTATE * 4);
    float* Cc  = (float*)alloc((size_t)2 * RTOT * NSTATE * 4);
    float* dtb = (float*)alloc((size_t)2 * RTOT * NH * 4);
    float* dAb = (float*)alloc((size_t)2 * RTOT * NH * 4);
    unsigned short* yb  = (unsigned short*)alloc((size_t)2 * RTOT * DI * 2);    // 33.5 MB
    unsigned short* yg  = (unsigned short*)alloc((size_t)2 * RTOT * DI * 2);    // 33.5 MB
    unsigned short* hbi = (unsigned short*)alloc((size_t)RTOT * DI * 2);        // 16.8 MB
    float* Pbuf = (float*)alloc((size_t)128 * NCH * 4);                          // 8 KB
    // Sbuf/Hbuf alias xb and win, which are dead after GEMM A (scan runs after conv).
    float* Sbuf = (float*)xb;   // 128*NCH*64*16*4 = 8.4 MB  (xb region is 8.4 MB)
    float* Hbuf = (float*)win;  // 8.4 MB (win region is 17 MB)
    (void)ws_size; (void)in_sizes; (void)n_in; (void)out_size;

    // weight / activation converts to bf16
    cvt_kernel<<<RTOT * DM / 1024, 256, 0, stream>>>(x, xb, RTOT * DM / 4);
    cvt_kernel<<<DIP * DM / 1024, 256, 0, stream>>>(fin, win, DIP * DM / 4);
    cvt_kernel<<<DIP * DM / 1024, 256, 0, stream>>>(bin, win + (size_t)DIP * DM, DIP * DM / 4);
    cvt_kernel<<<DM * DI / 1024, 256, 0, stream>>>(fout, wo, DM * DI / 4);
    cvt_kernel<<<DM * DI / 1024, 256, 0, stream>>>(bout, wo + (size_t)DM * DI, DM * DI / 4);
    cvt_kernel<<<DM * DI / 1024, 256, 0, stream>>>(lw, wl, DM * DI / 4);

    // GEMM A: zxbcdt for both dirs (stacked weights)
    gemm_kernel<1><<<dim3(NW / 128, RTOT / 128), 256, 0, stream>>>(
        xb, win, zx, RTOT, NW, DM, NW, 0, nullptr, nullptr);

    // conv + silu + split (fwd causal, bwd anti-causal)
    conv_kernel<<<dim3((CDIM + 255) / 256, LSEQ, 4), 256, 0, stream>>>(
        zx, fcw, fcb, bcw, bcb, xs, Bc, Cc);

    // dt softplus + dA
    dt_kernel<<<(2 * NB * LSEQ * NH) / 256, 256, 0, stream>>>(
        zx, fdtb, fAlog, bdtb, bAlog, dtb, dAb);

    // chunked scan: A) per-chunk states, B) combine, C) per-chunk scan+y
    chunk_state_kernel<<<dim3(NH, 4, NCH - 1), 64, 0, stream>>>(
        xs, Bc, dtb, dAb, Sbuf, Pbuf);
    chunk_combine_kernel<<<128, 64, 0, stream>>>(Sbuf, Pbuf, Hbuf);
    chunk_scan_kernel<<<dim3(NH, 4, NCH), 64, 0, stream>>>(
        xs, Bc, Cc, dtb, dAb, fDp, bDp, Hbuf, yb);

    // gate + RMSNorm
    gatenorm_kernel<<<dim3(RTOT, 2), 256, 0, stream>>>(yb, zx, fnw, bnw, yg);

    // GEMM B: out_proj per dir -> hbi (concat along cols)
    gemm_kernel<1><<<dim3(DM / 128, RTOT / 128), 256, 0, stream>>>(
        yg, wo, hbi, RTOT, DM, DI, DI, 0, nullptr, nullptr);
    gemm_kernel<1><<<dim3(DM / 128, RTOT / 128), 256, 0, stream>>>(
        yg + (size_t)RTOT * DI, wo + (size_t)DM * DI, hbi, RTOT, DM, DI, DI, DM, nullptr, nullptr);

    // GEMM C: layer out proj + residual epilogue
    gemm_kernel<2><<<dim3(DM / 128, RTOT / 128), 256, 0, stream>>>(
        hbi, wl, d_out, RTOT, DM, DI, DM, 0, x, lsc);
}

// Round 3
// 386.189 us; speedup vs baseline: 3.3397x; 1.2508x over previous
//
#include <hip/hip_runtime.h>

// ---------------- helpers ----------------
typedef __attribute__((ext_vector_type(8))) short bf16x8;   // 8 bf16 (4 VGPRs)
typedef __attribute__((ext_vector_type(4))) float f32x4;

#define DEV static __device__ __forceinline__

DEV float b2f(unsigned short u) {
    union { unsigned int u; float f; } c; c.u = ((unsigned int)u) << 16; return c.f;
}
DEV unsigned short f2b(float f) {
    union { float f; unsigned int u; } c; c.f = f;
    unsigned int u = c.u + 0x7fffu + ((c.u >> 16) & 1u);
    return (unsigned short)(u >> 16);
}
DEV float silu_f(float v) { return v / (1.f + __expf(-v)); }

#define GLD16(gp, lp) __builtin_amdgcn_global_load_lds( \
    (const __attribute__((address_space(1))) void*)(gp), \
    (__attribute__((address_space(3))) void*)(lp), 16, 0, 0)

// sizes
#define LSEQ 2048
#define NB 2
#define RTOT 4096          // NB*LSEQ
#define DM 1024
#define DI 2048
#define NH 32
#define HP 64
#define NSTATE 16
#define CDIM 2080
#define DIP 4160           // per-dir in_proj width
#define NW 8320            // stacked width
#define QCH 128            // scan chunk length
#define NCH (LSEQ / QCH)   // 16 chunks

// ---------------- batched f32 -> bf16 convert ----------------
struct CvtJobs {
    const float* src[6];
    unsigned short* dst[6];
    int n4[6];
};
__global__ __launch_bounds__(256) void cvtb_kernel(CvtJobs j) {
    const int jb = blockIdx.y;
    const int i = blockIdx.x * 256 + threadIdx.x;
    if (i >= j.n4[jb]) return;
    float4 v = ((const float4*)j.src[jb])[i];
    union { unsigned short s[4]; uint2 u; } p;
    p.s[0] = f2b(v.x); p.s[1] = f2b(v.y); p.s[2] = f2b(v.z); p.s[3] = f2b(v.w);
    ((uint2*)j.dst[jb])[i] = p.u;
}

// ---------------- bf16 MFMA GEMM, 128xBN tile, B given transposed (N x K) ----------------
// EPI: 1 = store bf16, 2 = out = ex + v*esc[col] (f32)
// grid.z selects (A,BT,coff) pair for fused dual-GEMM.
template<int BN_T, int EPI>
__global__ __launch_bounds__(256, 2) void gemm_kernel(
    const unsigned short* __restrict__ A0,    // M x K row-major bf16
    const unsigned short* __restrict__ BT0,   // N x K row-major bf16
    const unsigned short* __restrict__ A1,
    const unsigned short* __restrict__ BT1,
    void* __restrict__ Cout,
    int M, int N, int K, int ldc, int coff0, int coff1,
    const float* __restrict__ ex, const float* __restrict__ esc)
{
    constexpr int NI = BN_T / 32;             // per-wave n-fragments
    constexpr int BI = BN_T * 64 / (8 * 256); // B staging iters
    __shared__ unsigned short lA[128 * 64];
    __shared__ unsigned short lB[BN_T * 64];

    const unsigned short* A  = blockIdx.z ? A1 : A0;
    const unsigned short* BT = blockIdx.z ? BT1 : BT0;
    const int coff = blockIdx.z ? coff1 : coff0;

    // ---- block swizzle: bijective XCD chunk (m204) + gm=8 group walk ----
    const int nbx = gridDim.x, nby = gridDim.y;
    const int nwg = nbx * nby;
    int id = blockIdx.y * nbx + blockIdx.x;
    {
        const int q = nwg >> 3, r = nwg & 7;
        const int xcd = id & 7, off = id >> 3;
        id = (xcd < r) ? (xcd * (q + 1) + off) : (r * (q + 1) + (xcd - r) * q + off);
    }
    const int gm = 8;
    const int gidx = id / (gm * nbx);
    const int rem  = id - gidx * gm * nbx;
    const int width = min(gm, nby - gidx * gm);
    const int bm = (gidx * gm + rem % width) * 128;
    const int bn = (rem / width) * BN_T;

    const int tid  = threadIdx.x;
    const int wave = tid >> 6, lane = tid & 63;
    const int wm   = (wave >> 1) * 64, wn = (wave & 1) * (BN_T / 2);
    const int lr   = lane & 15, lq = lane >> 4;

    f32x4 acc[4][NI];
#pragma unroll
    for (int i = 0; i < 4; ++i)
#pragma unroll
        for (int j = 0; j < NI; ++j) acc[i][j] = (f32x4){0.f, 0.f, 0.f, 0.f};

    for (int k0 = 0; k0 < K; k0 += 64) {
#pragma unroll
        for (int i = 0; i < 4; ++i) {
            int c = tid + i * 256;
            int row = c >> 3, col = (c & 7) << 3;
            GLD16(A + (size_t)(bm + row) * K + (k0 + col), &lA[(i * 256 + (tid & ~63)) * 8]);
        }
#pragma unroll
        for (int i = 0; i < BI; ++i) {
            int c = tid + i * 256;
            int row = c >> 3, col = (c & 7) << 3;
            GLD16(BT + (size_t)(bn + row) * K + (k0 + col), &lB[(i * 256 + (tid & ~63)) * 8]);
        }
        __syncthreads();
#pragma unroll
        for (int kk = 0; kk < 64; kk += 32) {
            bf16x8 af[4], bf[NI];
#pragma unroll
            for (int mi = 0; mi < 4; ++mi)
                af[mi] = *(const bf16x8*)&lA[(wm + mi * 16 + lr) * 64 + kk + lq * 8];
#pragma unroll
            for (int ni = 0; ni < NI; ++ni)
                bf[ni] = *(const bf16x8*)&lB[(wn + ni * 16 + lr) * 64 + kk + lq * 8];
#pragma unroll
            for (int mi = 0; mi < 4; ++mi)
#pragma unroll
                for (int ni = 0; ni < NI; ++ni)
                    acc[mi][ni] = __builtin_amdgcn_mfma_f32_16x16x32_bf16(af[mi], bf[ni], acc[mi][ni], 0, 0, 0);
        }
        __syncthreads();
    }

#pragma unroll
    for (int mi = 0; mi < 4; ++mi)
#pragma unroll
        for (int ni = 0; ni < NI; ++ni)
#pragma unroll
            for (int r = 0; r < 4; ++r) {
                int grow = bm + wm + mi * 16 + lq * 4 + r;
                int gcol = bn + wn + ni * 16 + lr;
                float v = acc[mi][ni][r];
                if (EPI == 1) {
                    ((unsigned short*)Cout)[(size_t)grow * ldc + coff + gcol] = f2b(v);
                } else {
                    size_t idx = (size_t)grow * ldc + gcol;
                    ((float*)Cout)[idx] = ex[idx] + v * esc[gcol];
                }
            }
}

// ---------------- depthwise conv: sliding-window, each input read once ----------------
#define TCV 64
__global__ __launch_bounds__(256) void conv_kernel(
    const unsigned short* __restrict__ ZX,   // [4096][8320] bf16
    const float* __restrict__ cwF, const float* __restrict__ cbF,
    const float* __restrict__ cwB, const float* __restrict__ cbB,
    unsigned short* __restrict__ xs,         // [2][4096][2048] bf16
    float* __restrict__ Bc, float* __restrict__ Cc)  // [(d*2+b)*L+t][16]
{
    const int c = blockIdx.x * 256 + threadIdx.x;
    if (c >= CDIM) return;
    const int t0 = blockIdx.y * TCV;
    const int db = blockIdx.z;
    const int d = db >> 1, b = db & 1;
    const float* cw = d ? cwB : cwF;
    const float* cb = d ? cbB : cbF;
    float4 w = *(const float4*)&cw[c * 4];
    const float bias = cb[c];
    const unsigned short* base = ZX + (size_t)d * DIP + DI + c;  // + row*NW

    auto ldg = [&](int t) -> float {
        return (t >= 0 && t < LSEQ) ? b2f(base[(size_t)(b * LSEQ + t) * NW]) : 0.f;
    };
    auto emit = [&](int t, float acc) {
        float v = silu_f(acc);
        const int row = b * LSEQ + t;
        if (c < DI) {
            xs[((size_t)d * RTOT + row) * DI + c] = f2b(v);
        } else if (c < DI + NSTATE) {
            Bc[((size_t)db * LSEQ + t) * NSTATE + (c - DI)] = v;
        } else {
            Cc[((size_t)db * LSEQ + t) * NSTATE + (c - DI - NSTATE)] = v;
        }
    };

    if (d == 0) {
        // y[t] = w0*v[t-3] + w1*v[t-2] + w2*v[t-1] + w3*v[t]
        float v0 = ldg(t0 - 3), v1 = ldg(t0 - 2), v2 = ldg(t0 - 1), vt = ldg(t0);
#pragma unroll 4
        for (int i = 0; i < TCV; ++i) {
            float vn = (i < TCV - 1) ? ldg(t0 + i + 1) : 0.f;
            emit(t0 + i, bias + w.x * v0 + w.y * v1 + w.z * v2 + w.w * vt);
            v0 = v1; v1 = v2; v2 = vt; vt = vn;
        }
    } else {
        // y[t] = w3*v[t] + w2*v[t+1] + w1*v[t+2] + w0*v[t+3]
        float v3 = ldg(t0 + TCV + 2), v2 = ldg(t0 + TCV + 1), v1 = ldg(t0 + TCV), vt = ldg(t0 + TCV - 1);
#pragma unroll 4
        for (int i = TCV - 1; i >= 0; --i) {
            float vn = (i > 0) ? ldg(t0 + i - 1) : 0.f;
            emit(t0 + i, bias + w.w * vt + w.z * v1 + w.y * v2 + w.x * v3);
            v3 = v2; v2 = v1; v1 = vt; vt = vn;
        }
    }
}

// ---------------- dt: softplus + dA ----------------
__global__ __launch_bounds__(256) void dt_kernel(
    const unsigned short* __restrict__ ZX,
    const float* __restrict__ biasF, const float* __restrict__ AlogF,
    const float* __restrict__ biasB, const float* __restrict__ AlogB,
    float* __restrict__ dtb, float* __restrict__ dAb)
{
    int i = blockIdx.x * 256 + threadIdx.x;          // [d][b][t][h]
    int h = i & 31, t = (i >> 5) & 2047, b = (i >> 16) & 1, d = (i >> 17) & 1;
    float raw = b2f(ZX[(size_t)(b * LSEQ + t) * NW + d * DIP + (DI + CDIM) + h]);
    float bias = (d ? biasB : biasF)[h];
    float Alog = (d ? AlogB : AlogF)[h];
    float xv = raw + bias;
    float dt = (xv > 20.f) ? xv : __logf(1.f + __expf(xv));
    float A = -__expf(Alog);
    dtb[i] = dt;
    dAb[i] = __expf(dt * A);
}

#define LD16V(dst, ptr) do { const float4* _p = (const float4*)(ptr); \
    float4 _q0 = _p[0], _q1 = _p[1], _q2 = _p[2], _q3 = _p[3]; \
    dst[0]=_q0.x; dst[1]=_q0.y; dst[2]=_q0.z; dst[3]=_q0.w; \
    dst[4]=_q1.x; dst[5]=_q1.y; dst[6]=_q1.z; dst[7]=_q1.w; \
    dst[8]=_q2.x; dst[9]=_q2.y; dst[10]=_q2.z; dst[11]=_q2.w; \
    dst[12]=_q3.x; dst[13]=_q3.y; dst[14]=_q3.z; dst[15]=_q3.w; } while (0)

#define ST16V(ptr, src) do { float4* _p = (float4*)(ptr); \
    _p[0] = make_float4(src[0],src[1],src[2],src[3]); \
    _p[1] = make_float4(src[4],src[5],src[6],src[7]); \
    _p[2] = make_float4(src[8],src[9],src[10],src[11]); \
    _p[3] = make_float4(src[12],src[13],src[14],src[15]); } while (0)

// ---------------- pass A: per-chunk zero-init state + decay product ----------------
__global__ __launch_bounds__(64) void chunk_state_kernel(
    const unsigned short* __restrict__ xs,
    const float* __restrict__ Bc,
    const float* __restrict__ dtb, const float* __restrict__ dAb,
    float* __restrict__ Sbuf,               // [128][NCH][64][16]
    float* __restrict__ Pbuf)               // [128][NCH]
{
    const int h = blockIdx.x, db = blockIdx.y, c = blockIdx.z;
    const int d = db >> 1, b = db & 1;
    const int lane = threadIdx.x;
    float hs[16];
#pragma unroll
    for (int n = 0; n < 16; ++n) hs[n] = 0.f;
    float pacc = 1.f;
    const size_t dbase = (size_t)d * RTOT;
    const int s0 = c * QCH;

    float Bs[16], xv, dtv, dAv;
    float Bn[16], xn, dtn, dAn;
    {
        const int t = d ? (LSEQ - 1 - s0) : s0;
        const size_t row = (size_t)b * LSEQ + t, rdb = (size_t)db * LSEQ + t;
        xv  = b2f(xs[(dbase + row) * DI + h * HP + lane]);
        dtv = dtb[rdb * 32 + h]; dAv = dAb[rdb * 32 + h];
        LD16V(Bs, Bc + rdb * 16);
    }
#pragma unroll 2
    for (int i = 0; i < QCH; ++i) {
        const int sn = s0 + ((i < QCH - 1) ? i + 1 : i);
        const int tn = d ? (LSEQ - 1 - sn) : sn;
        {
            const size_t rown = (size_t)b * LSEQ + tn, rdbn = (size_t)db * LSEQ + tn;
            xn  = b2f(xs[(dbase + rown) * DI + h * HP + lane]);
            dtn = dtb[rdbn * 32 + h]; dAn = dAb[rdbn * 32 + h];
            LD16V(Bn, Bc + rdbn * 16);
        }
        const float dtx = dtv * xv;
#pragma unroll
        for (int n = 0; n < 16; ++n) hs[n] = fmaf(hs[n], dAv, Bs[n] * dtx);
        pacc *= dAv;
        xv = xn; dtv = dtn; dAv = dAn;
#pragma unroll
        for (int n = 0; n < 16; ++n) Bs[n] = Bn[n];
    }
    float* Sp = Sbuf + (((size_t)(db * NH + h)) * NCH + c) * 1024 + lane * 16;
    ST16V(Sp, hs);
    if (lane == 0) Pbuf[(db * NH + h) * NCH + c] = pacc;
}

// ---------------- pass B: sequential combine over chunks (tiny) ----------------
__global__ __launch_bounds__(64) void chunk_combine_kernel(
    const float* __restrict__ Sbuf, const float* __restrict__ Pbuf,
    float* __restrict__ Hbuf)               // [128][NCH][64][16]
{
    const int idx = blockIdx.x;
    const int lane = threadIdx.x;
    float hs[16];
#pragma unroll
    for (int n = 0; n < 16; ++n) hs[n] = 0.f;
    float* H0 = Hbuf + ((size_t)idx * NCH) * 1024 + lane * 16;
    ST16V(H0, hs);
    for (int c = 0; c < NCH - 1; ++c) {
        const float* Sp = Sbuf + ((size_t)idx * NCH + c) * 1024 + lane * 16;
        float S[16];
        LD16V(S, Sp);
        const float P = Pbuf[idx * NCH + c];
#pragma unroll
        for (int n = 0; n < 16; ++n) hs[n] = fmaf(hs[n], P, S[n]);
        float* Hp = Hbuf + ((size_t)idx * NCH + c + 1) * 1024 + lane * 16;
        ST16V(Hp, hs);
    }
}

// ---------------- pass C: per-chunk scan from Hinit, emit y ----------------
__global__ __launch_bounds__(64) void chunk_scan_kernel(
    const unsigned short* __restrict__ xs,
    const float* __restrict__ Bc, const float* __restrict__ Cc,
    const float* __restrict__ dtb, const float* __restrict__ dAb,
    const float* __restrict__ DpF, const float* __restrict__ DpB,
    const float* __restrict__ Hbuf,
    unsigned short* __restrict__ ybuf)       // [2][4096][2048]
{
    const int h = blockIdx.x, db = blockIdx.y, c = blockIdx.z;
    const int d = db >> 1, b = db & 1;
    const int lane = threadIdx.x;
    const float Dp = (d ? DpB : DpF)[h];
    float hs[16];
    {
        const float* Hp = Hbuf + ((size_t)(db * NH + h) * NCH + c) * 1024 + lane * 16;
        LD16V(hs, Hp);
    }
    const size_t dbase = (size_t)d * RTOT;
    const int s0 = c * QCH;

    float Bs[16], Cs[16], xv, dtv, dAv;
    float Bn[16], Cn[16], xn, dtn, dAn;
    {
        const int t = d ? (LSEQ - 1 - s0) : s0;
        const size_t row = (size_t)b * LSEQ + t, rdb = (size_t)db * LSEQ + t;
        xv  = b2f(xs[(dbase + row) * DI + h * HP + lane]);
        dtv = dtb[rdb * 32 + h]; dAv = dAb[rdb * 32 + h];
        LD16V(Bs, Bc + rdb * 16);
        LD16V(Cs, Cc + rdb * 16);
    }
#pragma unroll 2
    for (int i = 0; i < QCH; ++i) {
        const int sn = s0 + ((i < QCH - 1) ? i + 1 : i);
        const int tn = d ? (LSEQ - 1 - sn) : sn;
        {
            const size_t rown = (size_t)b * LSEQ + tn, rdbn = (size_t)db * LSEQ + tn;
            xn  = b2f(xs[(dbase + rown) * DI + h * HP + lane]);
            dtn = dtb[rdbn * 32 + h]; dAn = dAb[rdbn * 32 + h];
            LD16V(Bn, Bc + rdbn * 16);
            LD16V(Cn, Cc + rdbn * 16);
        }
        const float dtx = dtv * xv;
        float yq[4] = {0.f, 0.f, 0.f, 0.f};
#pragma unroll
        for (int n = 0; n < 16; ++n) {
            hs[n] = fmaf(hs[n], dAv, Bs[n] * dtx);
            yq[n & 3] = fmaf(Cs[n], hs[n], yq[n & 3]);
        }
        const int t = d ? (LSEQ - 1 - (s0 + i)) : (s0 + i);
        const size_t row = (size_t)b * LSEQ + t;
        ybuf[(dbase + row) * DI + h * HP + lane] = f2b(((yq[0] + yq[1]) + (yq[2] + yq[3])) + Dp * xv);

        xv = xn; dtv = dtn; dAv = dAn;
#pragma unroll
        for (int n = 0; n < 16; ++n) { Bs[n] = Bn[n]; Cs[n] = Cn[n]; }
    }
}

// ---------------- gate (silu(z)) + RMSNorm -> bf16 ----------------
__global__ __launch_bounds__(256) void gatenorm_kernel(
    const unsigned short* __restrict__ ybuf, const unsigned short* __restrict__ ZX,
    const float* __restrict__ nwF, const float* __restrict__ nwB,
    unsigned short* __restrict__ yg)
{
    const int r = blockIdx.x;      // 0..4095 (b*L+t)
    const int d = blockIdx.y;
    const int tid = threadIdx.x;
    const float* nw = d ? nwB : nwF;
    const int c0 = tid * 8;
    const unsigned short* yp = ybuf + ((size_t)d * RTOT + r) * DI + c0;
    const unsigned short* zp = ZX + (size_t)r * NW + d * DIP + c0;
    uint4 yv = *(const uint4*)yp;
    uint4 zv = *(const uint4*)zp;
    unsigned int yw[4] = {yv.x, yv.y, yv.z, yv.w};
    unsigned int zw[4] = {zv.x, zv.y, zv.z, zv.w};
    float g[8]; float ss = 0.f;
#pragma unroll
    for (int i = 0; i < 8; ++i) {
        unsigned short yu = (i & 1) ? (unsigned short)(yw[i >> 1] >> 16) : (unsigned short)(yw[i >> 1] & 0xffff);
        unsigned short zu = (i & 1) ? (unsigned short)(zw[i >> 1] >> 16) : (unsigned short)(zw[i >> 1] & 0xffff);
        float y = b2f(yu), z = b2f(zu);
        float gv = y * silu_f(z);
        g[i] = gv; ss += gv * gv;
    }
#pragma unroll
    for (int m = 1; m < 64; m <<= 1) ss += __shfl_xor(ss, m, 64);
    __shared__ float red[4];
    if ((tid & 63) == 0) red[tid >> 6] = ss;
    __syncthreads();
    float tot = red[0] + red[1] + red[2] + red[3];
    float sc = rsqrtf(tot * (1.f / 2048.f) + 1e-5f);
    union { unsigned short s[8]; uint4 u; } o;
#pragma unroll
    for (int i = 0; i < 8; ++i) o.s[i] = f2b(g[i] * sc * nw[c0 + i]);
    *(uint4*)(yg + ((size_t)d * RTOT + r) * DI + c0) = o.u;
}

// ---------------- host ----------------
extern "C" void kernel_launch(void* const* d_in, const int* in_sizes, int n_in,
                              void* d_out, int out_size, void* d_ws, size_t ws_size,
                              hipStream_t stream)
{
    const float* x     = (const float*)d_in[0];
    const float* fin   = (const float*)d_in[1];
    const float* fcw   = (const float*)d_in[2];
    const float* fcb   = (const float*)d_in[3];
    const float* fdtb  = (const float*)d_in[4];
    const float* fAlog = (const float*)d_in[5];
    const float* fDp   = (const float*)d_in[6];
    const float* fnw   = (const float*)d_in[7];
    const float* fout  = (const float*)d_in[8];
    const float* bin   = (const float*)d_in[9];
    const float* bcw   = (const float*)d_in[10];
    const float* bcb   = (const float*)d_in[11];
    const float* bdtb  = (const float*)d_in[12];
    const float* bAlog = (const float*)d_in[13];
    const float* bDp   = (const float*)d_in[14];
    const float* bnw   = (const float*)d_in[15];
    const float* bout  = (const float*)d_in[16];
    const float* lw    = (const float*)d_in[17];
    const float* lsc   = (const float*)d_in[18];

    char* w = (char*)d_ws;
    auto alloc = [&](size_t bytes) { char* p = w; w += (bytes + 255) & ~(size_t)255; return p; };
    unsigned short* xb  = (unsigned short*)alloc((size_t)RTOT * DM * 2);
    unsigned short* win = (unsigned short*)alloc((size_t)NW * DM * 2);
    unsigned short* wo  = (unsigned short*)alloc((size_t)2 * DM * DI * 2);
    unsigned short* wl  = (unsigned short*)alloc((size_t)DM * DI * 2);
    unsigned short* zx  = (unsigned short*)alloc((size_t)RTOT * NW * 2);
    unsigned short* xs  = (unsigned short*)alloc((size_t)2 * RTOT * DI * 2);
    float* Bc  = (float*)alloc((size_t)2 * RTOT * NSTATE * 4);
    float* Cc  = (float*)alloc((size_t)2 * RTOT * NSTATE * 4);
    float* dtb = (float*)alloc((size_t)2 * RTOT * NH * 4);
    float* dAb = (float*)alloc((size_t)2 * RTOT * NH * 4);
    unsigned short* yb  = (unsigned short*)alloc((size_t)2 * RTOT * DI * 2);
    unsigned short* yg  = (unsigned short*)alloc((size_t)2 * RTOT * DI * 2);
    unsigned short* hbi = (unsigned short*)alloc((size_t)RTOT * DI * 2);
    float* Pbuf = (float*)alloc((size_t)128 * NCH * 4);
    // Sbuf/Hbuf alias xb and win (dead after GEMM A).
    float* Sbuf = (float*)xb;
    float* Hbuf = (float*)win;
    (void)ws_size; (void)in_sizes; (void)n_in; (void)out_size;

    // batched weight/activation converts to bf16 (one dispatch)
    CvtJobs jobs;
    jobs.src[0] = x;    jobs.dst[0] = xb;                        jobs.n4[0] = RTOT * DM / 4;
    jobs.src[1] = fin;  jobs.dst[1] = win;                       jobs.n4[1] = DIP * DM / 4;
    jobs.src[2] = bin;  jobs.dst[2] = win + (size_t)DIP * DM;    jobs.n4[2] = DIP * DM / 4;
    jobs.src[3] = fout; jobs.dst[3] = wo;                        jobs.n4[3] = DM * DI / 4;
    jobs.src[4] = bout; jobs.dst[4] = wo + (size_t)DM * DI;      jobs.n4[4] = DM * DI / 4;
    jobs.src[5] = lw;   jobs.dst[5] = wl;                        jobs.n4[5] = DM * DI / 4;
    cvtb_kernel<<<dim3((DIP * DM / 4 + 255) / 256, 6), 256, 0, stream>>>(jobs);

    // GEMM A: zxbcdt for both dirs (stacked weights)
    gemm_kernel<128, 1><<<dim3(NW / 128, RTOT / 128), 256, 0, stream>>>(
        xb, win, nullptr, nullptr, zx, RTOT, NW, DM, NW, 0, 0, nullptr, nullptr);

    // conv + silu + split (fwd causal, bwd anti-causal), sliding-window
    conv_kernel<<<dim3((CDIM + 255) / 256, LSEQ / TCV, 4), 256, 0, stream>>>(
        zx, fcw, fcb, bcw, bcb, xs, Bc, Cc);

    // dt softplus + dA
    dt_kernel<<<(2 * NB * LSEQ * NH) / 256, 256, 0, stream>>>(
        zx, fdtb, fAlog, bdtb, bAlog, dtb, dAb);

    // chunked scan: A) per-chunk states, B) combine, C) per-chunk scan+y
    chunk_state_kernel<<<dim3(NH, 4, NCH - 1), 64, 0, stream>>>(
        xs, Bc, dtb, dAb, Sbuf, Pbuf);
    chunk_combine_kernel<<<128, 64, 0, stream>>>(Sbuf, Pbuf, Hbuf);
    chunk_scan_kernel<<<dim3(NH, 4, NCH), 64, 0, stream>>>(
        xs, Bc, Cc, dtb, dAb, fDp, bDp, Hbuf, yb);

    // gate + RMSNorm
    gatenorm_kernel<<<dim3(RTOT, 2), 256, 0, stream>>>(yb, zx, fnw, bnw, yg);

    // GEMM B: out_proj both dirs fused in one dispatch (grid.z=2)
    gemm_kernel<128, 1><<<dim3(DM / 128, RTOT / 128, 2), 256, 0, stream>>>(
        yg, wo, yg + (size_t)RTOT * DI, wo + (size_t)DM * DI,
        hbi, RTOT, DM, DI, DI, 0, DM, nullptr, nullptr);

    // GEMM C: layer out proj + residual epilogue (BN=64 -> 512 blocks)
    gemm_kernel<64, 2><<<dim3(DM / 64, RTOT / 128), 256, 0, stream>>>(
        hbi, wl, nullptr, nullptr, d_out, RTOT, DM, DI, DM, 0, 0, x, lsc);
}

// Round 4
// 383.827 us; speedup vs baseline: 3.3602x; 1.0062x over previous
//
#include <hip/hip_runtime.h>

// ---------------- helpers ----------------
typedef __attribute__((ext_vector_type(8))) short bf16x8;   // 8 bf16 (4 VGPRs)
typedef __attribute__((ext_vector_type(4))) float f32x4;

#define DEV static __device__ __forceinline__

DEV float b2f(unsigned short u) {
    union { unsigned int u; float f; } c; c.u = ((unsigned int)u) << 16; return c.f;
}
DEV unsigned short f2b(float f) {
    union { float f; unsigned int u; } c; c.f = f;
    unsigned int u = c.u + 0x7fffu + ((c.u >> 16) & 1u);
    return (unsigned short)(u >> 16);
}
DEV float silu_f(float v) { return v / (1.f + __expf(-v)); }

#define GLD16(gp, lp) __builtin_amdgcn_global_load_lds( \
    (const __attribute__((address_space(1))) void*)(gp), \
    (__attribute__((address_space(3))) void*)(lp), 16, 0, 0)

// sizes
#define LSEQ 2048
#define NB 2
#define RTOT 4096          // NB*LSEQ
#define DM 1024
#define DI 2048
#define NH 32
#define HP 64
#define NSTATE 16
#define CDIM 2080
#define DIP 4160           // per-dir in_proj width
#define NW 8320            // stacked width
#define QCH 128            // scan chunk length
#define NCH (LSEQ / QCH)   // 16 chunks

// ---------------- batched f32 -> bf16 convert ----------------
struct CvtJobs {
    const float* src[6];
    unsigned short* dst[6];
    int n4[6];
};
__global__ __launch_bounds__(256) void cvtb_kernel(CvtJobs j) {
    const int jb = blockIdx.y;
    const int i = blockIdx.x * 256 + threadIdx.x;
    if (i >= j.n4[jb]) return;
    float4 v = ((const float4*)j.src[jb])[i];
    union { unsigned short s[4]; uint2 u; } p;
    p.s[0] = f2b(v.x); p.s[1] = f2b(v.y); p.s[2] = f2b(v.z); p.s[3] = f2b(v.w);
    ((uint2*)j.dst[jb])[i] = p.u;
}

// ---------------- pipelined bf16 MFMA GEMM ----------------
// BM=256, BN=128, BK=64, 8 waves (2M x 4N), 3 LDS buffers, counted vmcnt(6).
// A: M x K row-major; BT: N x K row-major. EPI 1 = bf16 store; 2 = f32 ex + v*esc.
// grid.z selects (A,BT,coff) for fused dual-GEMM.

// stage one 8KB quantum (64 rows x 64 cols bf16) of a tile into LDS.
// dest linear; SOURCE chunk pre-swizzled with key (row&7)  [rule #21]
#define STG(Gbase, rowbase, reg, qq, k0s) do { \
    int _r = (qq) * 64 + (tid >> 3); \
    const unsigned short* _s = (Gbase) + (size_t)((rowbase) + _r) * K + (k0s) + (((tid & 7) ^ (_r & 7)) << 3); \
    GLD16(_s, (reg) + (qq) * 4096 + ((tid >> 6) << 9)); } while (0)

#define BAR_WAIT \
    __builtin_amdgcn_s_barrier(); __builtin_amdgcn_sched_barrier(0); \
    asm volatile("s_waitcnt lgkmcnt(0)" ::: "memory"); \
    __builtin_amdgcn_sched_barrier(0);

#define ENDBAR \
    __builtin_amdgcn_s_barrier(); __builtin_amdgcn_sched_barrier(0);

#define MFMA8(mh) \
    __builtin_amdgcn_s_setprio(1); \
    acc[(mh)*4+0][0] = __builtin_amdgcn_mfma_f32_16x16x32_bf16(af0, bf0, acc[(mh)*4+0][0], 0, 0, 0); \
    acc[(mh)*4+0][1] = __builtin_amdgcn_mfma_f32_16x16x32_bf16(af0, bf1, acc[(mh)*4+0][1], 0, 0, 0); \
    acc[(mh)*4+1][0] = __builtin_amdgcn_mfma_f32_16x16x32_bf16(af1, bf0, acc[(mh)*4+1][0], 0, 0, 0); \
    acc[(mh)*4+1][1] = __builtin_amdgcn_mfma_f32_16x16x32_bf16(af1, bf1, acc[(mh)*4+1][1], 0, 0, 0); \
    acc[(mh)*4+2][0] = __builtin_amdgcn_mfma_f32_16x16x32_bf16(af2, bf0, acc[(mh)*4+2][0], 0, 0, 0); \
    acc[(mh)*4+2][1] = __builtin_amdgcn_mfma_f32_16x16x32_bf16(af2, bf1, acc[(mh)*4+2][1], 0, 0, 0); \
    acc[(mh)*4+3][0] = __builtin_amdgcn_mfma_f32_16x16x32_bf16(af3, bf0, acc[(mh)*4+3][0], 0, 0, 0); \
    acc[(mh)*4+3][1] = __builtin_amdgcn_mfma_f32_16x16x32_bf16(af3, bf1, acc[(mh)*4+3][1], 0, 0, 0); \
    __builtin_amdgcn_s_setprio(0);

template<int EPI>
__global__ __launch_bounds__(512, 1) void gemm3_kernel(
    const unsigned short* __restrict__ A0, const unsigned short* __restrict__ BT0,
    const unsigned short* __restrict__ A1, const unsigned short* __restrict__ BT1,
    void* __restrict__ Cout,
    int K, int ldc, int coff0, int coff1,
    const float* __restrict__ ex, const float* __restrict__ esc)
{
    __shared__ unsigned short lds[3 * 24576];   // 3 x (A 256x64 + B 128x64) = 144 KiB

    const unsigned short* __restrict__ A  = blockIdx.z ? A1 : A0;
    const unsigned short* __restrict__ BT = blockIdx.z ? BT1 : BT0;
    const int coff = blockIdx.z ? coff1 : coff0;

    // bijective XCD chunk (m204) + gm=8 group walk
    const int nbx = gridDim.x, nby = gridDim.y;
    const int nwg = nbx * nby;
    int id = blockIdx.y * nbx + blockIdx.x;
    {
        const int q = nwg >> 3, r = nwg & 7;
        const int xcd = id & 7, off = id >> 3;
        id = (xcd < r) ? (xcd * (q + 1) + off) : (r * (q + 1) + (xcd - r) * q + off);
    }
    const int gm = 8;
    const int gidx = id / (gm * nbx);
    const int rem  = id - gidx * gm * nbx;
    const int width = min(gm, nby - gidx * gm);
    const int bm = (gidx * gm + rem % width) * 256;
    const int bn = (rem / width) * 128;

    const int tid  = threadIdx.x;
    const int wave = tid >> 6, lane = tid & 63;
    const int wm = wave >> 2, wn = wave & 3;       // 2 M-waves x 4 N-waves
    const int lr = lane & 15, lq = lane >> 4;
    const int swz = (lr & 7) << 3;                 // T2 read-side XOR key
    const int KT = K >> 6;

    const int arow0 = (wm * 128 + lr) * 64;        // + mf*1024
    const int brow0 = (wn * 32 + lr) * 64;         // + ni*1024
    const int c0v = (lq * 8) ^ swz;                // ks=0 column
    const int c1v = (32 + lq * 8) ^ swz;           // ks=1 column

    f32x4 acc[8][2];
#pragma unroll
    for (int i = 0; i < 8; ++i) {
        acc[i][0] = (f32x4){0.f, 0.f, 0.f, 0.f};
        acc[i][1] = (f32x4){0.f, 0.f, 0.f, 0.f};
    }

    // ---- prologue: stage tiles 0 and 1 (6 quanta each), wait tile 0 ----
    {
        unsigned short* a0s = &lds[0];
        unsigned short* b0s = &lds[16384];
        unsigned short* a1s = &lds[24576];
        unsigned short* b1s = &lds[24576 + 16384];
        STG(A, bm, a0s, 0, 0); STG(A, bm, a0s, 1, 0); STG(A, bm, a0s, 2, 0); STG(A, bm, a0s, 3, 0);
        STG(BT, bn, b0s, 0, 0); STG(BT, bn, b0s, 1, 0);
        STG(A, bm, a1s, 0, 64); STG(A, bm, a1s, 1, 64); STG(A, bm, a1s, 2, 64); STG(A, bm, a1s, 3, 64);
        STG(BT, bn, b1s, 0, 64); STG(BT, bn, b1s, 1, 64);
        asm volatile("s_waitcnt vmcnt(6)" ::: "memory");
        __builtin_amdgcn_sched_barrier(0);
        __builtin_amdgcn_s_barrier();
        __builtin_amdgcn_sched_barrier(0);
    }

    int scur = 0;
    for (int kt = 0; kt < KT; ++kt) {
        const int sstg = (scur == 0) ? 2 : scur - 1;      // == (kt+2)%3
        const unsigned short* aC = &lds[scur * 24576];
        const unsigned short* bC = &lds[scur * 24576 + 16384];
        unsigned short* aS = &lds[sstg * 24576];
        unsigned short* bS = &lds[sstg * 24576 + 16384];
        const int k0s = (kt + 2) << 6;
        const bool dostage = (kt + 2) < KT;

        bf16x8 af0, af1, af2, af3, bf0, bf1;

        // ---- phase 0: (mh0, ks0) + B(ks0) frags; stage A q0,q1 of tile kt+2 ----
        bf0 = *(const bf16x8*)&bC[brow0 + c0v];
        bf1 = *(const bf16x8*)&bC[brow0 + 1024 + c0v];
        af0 = *(const bf16x8*)&aC[arow0 + c0v];
        af1 = *(const bf16x8*)&aC[arow0 + 1024 + c0v];
        af2 = *(const bf16x8*)&aC[arow0 + 2048 + c0v];
        af3 = *(const bf16x8*)&aC[arow0 + 3072 + c0v];
        if (dostage) { STG(A, bm, aS, 0, k0s); STG(A, bm, aS, 1, k0s); }
        BAR_WAIT;
        MFMA8(0);
        ENDBAR;

        // ---- phase 1: (mh1, ks0); stage A q2,q3 ----
        af0 = *(const bf16x8*)&aC[arow0 + 4096 + c0v];
        af1 = *(const bf16x8*)&aC[arow0 + 5120 + c0v];
        af2 = *(const bf16x8*)&aC[arow0 + 6144 + c0v];
        af3 = *(const bf16x8*)&aC[arow0 + 7168 + c0v];
        if (dostage) { STG(A, bm, aS, 2, k0s); STG(A, bm, aS, 3, k0s); }
        BAR_WAIT;
        MFMA8(1);
        ENDBAR;

        // ---- phase 2: (mh0, ks1) + B(ks1) frags; stage B q0 ----
        bf0 = *(const bf16x8*)&bC[brow0 + c1v];
        bf1 = *(const bf16x8*)&bC[brow0 + 1024 + c1v];
        af0 = *(const bf16x8*)&aC[arow0 + c1v];
        af1 = *(const bf16x8*)&aC[arow0 + 1024 + c1v];
        af2 = *(const bf16x8*)&aC[arow0 + 2048 + c1v];
        af3 = *(const bf16x8*)&aC[arow0 + 3072 + c1v];
        if (dostage) { STG(BT, bn, bS, 0, k0s); }
        BAR_WAIT;
        MFMA8(0);
        ENDBAR;

        // ---- phase 3: (mh1, ks1); stage B q1; tile-end counted vmcnt ----
        af0 = *(const bf16x8*)&aC[arow0 + 4096 + c1v];
        af1 = *(const bf16x8*)&aC[arow0 + 5120 + c1v];
        af2 = *(const bf16x8*)&aC[arow0 + 6144 + c1v];
        af3 = *(const bf16x8*)&aC[arow0 + 7168 + c1v];
        if (dostage) { STG(BT, bn, bS, 1, k0s); }
        BAR_WAIT;
        MFMA8(1);
        if (dostage) { asm volatile("s_waitcnt vmcnt(6)" ::: "memory"); }
        else         { asm volatile("s_waitcnt vmcnt(0)" ::: "memory"); }
        __builtin_amdgcn_sched_barrier(0);
        ENDBAR;

        scur = (scur == 2) ? 0 : scur + 1;
    }

    // ---- epilogue ----
#pragma unroll
    for (int mf = 0; mf < 8; ++mf)
#pragma unroll
        for (int ni = 0; ni < 2; ++ni)
#pragma unroll
            for (int r = 0; r < 4; ++r) {
                int grow = bm + wm * 128 + mf * 16 + lq * 4 + r;
                int gcol = bn + wn * 32 + ni * 16 + lr;
                float v = acc[mf][ni][r];
                if (EPI == 1) {
                    ((unsigned short*)Cout)[(size_t)grow * ldc + coff + gcol] = f2b(v);
                } else {
                    size_t idx = (size_t)grow * ldc + gcol;
                    ((float*)Cout)[idx] = ex[idx] + v * esc[gcol];
                }
            }
}

// ---------------- depthwise conv: sliding-window, each input read once ----------------
#define TCV 64
__global__ __launch_bounds__(256) void conv_kernel(
    const unsigned short* __restrict__ ZX,   // [4096][8320] bf16
    const float* __restrict__ cwF, const float* __restrict__ cbF,
    const float* __restrict__ cwB, const float* __restrict__ cbB,
    unsigned short* __restrict__ xs,         // [2][4096][2048] bf16
    float* __restrict__ Bc, float* __restrict__ Cc)  // [(d*2+b)*L+t][16]
{
    const int c = blockIdx.x * 256 + threadIdx.x;
    if (c >= CDIM) return;
    const int t0 = blockIdx.y * TCV;
    const int db = blockIdx.z;
    const int d = db >> 1, b = db & 1;
    const float* cw = d ? cwB : cwF;
    const float* cb = d ? cbB : cbF;
    float4 w = *(const float4*)&cw[c * 4];
    const float bias = cb[c];
    const unsigned short* base = ZX + (size_t)d * DIP + DI + c;  // + row*NW

    auto ldg = [&](int t) -> float {
        return (t >= 0 && t < LSEQ) ? b2f(base[(size_t)(b * LSEQ + t) * NW]) : 0.f;
    };
    auto emit = [&](int t, float acc) {
        float v = silu_f(acc);
        const int row = b * LSEQ + t;
        if (c < DI) {
            xs[((size_t)d * RTOT + row) * DI + c] = f2b(v);
        } else if (c < DI + NSTATE) {
            Bc[((size_t)db * LSEQ + t) * NSTATE + (c - DI)] = v;
        } else {
            Cc[((size_t)db * LSEQ + t) * NSTATE + (c - DI - NSTATE)] = v;
        }
    };

    if (d == 0) {
        float v0 = ldg(t0 - 3), v1 = ldg(t0 - 2), v2 = ldg(t0 - 1), vt = ldg(t0);
#pragma unroll 4
        for (int i = 0; i < TCV; ++i) {
            float vn = (i < TCV - 1) ? ldg(t0 + i + 1) : 0.f;
            emit(t0 + i, bias + w.x * v0 + w.y * v1 + w.z * v2 + w.w * vt);
            v0 = v1; v1 = v2; v2 = vt; vt = vn;
        }
    } else {
        float v3 = ldg(t0 + TCV + 2), v2 = ldg(t0 + TCV + 1), v1 = ldg(t0 + TCV), vt = ldg(t0 + TCV - 1);
#pragma unroll 4
        for (int i = TCV - 1; i >= 0; --i) {
            float vn = (i > 0) ? ldg(t0 + i - 1) : 0.f;
            emit(t0 + i, bias + w.w * vt + w.z * v1 + w.y * v2 + w.x * v3);
            v3 = v2; v2 = v1; v1 = vt; vt = vn;
        }
    }
}

// ---------------- dt: softplus + dA ----------------
__global__ __launch_bounds__(256) void dt_kernel(
    const unsigned short* __restrict__ ZX,
    const float* __restrict__ biasF, const float* __restrict__ AlogF,
    const float* __restrict__ biasB, const float* __restrict__ AlogB,
    float* __restrict__ dtb, float* __restrict__ dAb)
{
    int i = blockIdx.x * 256 + threadIdx.x;          // [d][b][t][h]
    int h = i & 31, t = (i >> 5) & 2047, b = (i >> 16) & 1, d = (i >> 17) & 1;
    float raw = b2f(ZX[(size_t)(b * LSEQ + t) * NW + d * DIP + (DI + CDIM) + h]);
    float bias = (d ? biasB : biasF)[h];
    float Alog = (d ? AlogB : AlogF)[h];
    float xv = raw + bias;
    float dt = (xv > 20.f) ? xv : __logf(1.f + __expf(xv));
    float A = -__expf(Alog);
    dtb[i] = dt;
    dAb[i] = __expf(dt * A);
}

#define LD16V(dst, ptr) do { const float4* _p = (const float4*)(ptr); \
    float4 _q0 = _p[0], _q1 = _p[1], _q2 = _p[2], _q3 = _p[3]; \
    dst[0]=_q0.x; dst[1]=_q0.y; dst[2]=_q0.z; dst[3]=_q0.w; \
    dst[4]=_q1.x; dst[5]=_q1.y; dst[6]=_q1.z; dst[7]=_q1.w; \
    dst[8]=_q2.x; dst[9]=_q2.y; dst[10]=_q2.z; dst[11]=_q2.w; \
    dst[12]=_q3.x; dst[13]=_q3.y; dst[14]=_q3.z; dst[15]=_q3.w; } while (0)

#define ST16V(ptr, src) do { float4* _p = (float4*)(ptr); \
    _p[0] = make_float4(src[0],src[1],src[2],src[3]); \
    _p[1] = make_float4(src[4],src[5],src[6],src[7]); \
    _p[2] = make_float4(src[8],src[9],src[10],src[11]); \
    _p[3] = make_float4(src[12],src[13],src[14],src[15]); } while (0)

// ---------------- pass A: per-chunk zero-init state + decay product ----------------
__global__ __launch_bounds__(64) void chunk_state_kernel(
    const unsigned short* __restrict__ xs,
    const float* __restrict__ Bc,
    const float* __restrict__ dtb, const float* __restrict__ dAb,
    float* __restrict__ Sbuf,               // [128][NCH][64][16]
    float* __restrict__ Pbuf)               // [128][NCH]
{
    const int h = blockIdx.x, db = blockIdx.y, c = blockIdx.z;
    const int d = db >> 1, b = db & 1;
    const int lane = threadIdx.x;
    float hs[16];
#pragma unroll
    for (int n = 0; n < 16; ++n) hs[n] = 0.f;
    float pacc = 1.f;
    const size_t dbase = (size_t)d * RTOT;
    const int s0 = c * QCH;

    float Bs[16], xv, dtv, dAv;
    float Bn[16], xn, dtn, dAn;
    {
        const int t = d ? (LSEQ - 1 - s0) : s0;
        const size_t row = (size_t)b * LSEQ + t, rdb = (size_t)db * LSEQ + t;
        xv  = b2f(xs[(dbase + row) * DI + h * HP + lane]);
        dtv = dtb[rdb * 32 + h]; dAv = dAb[rdb * 32 + h];
        LD16V(Bs, Bc + rdb * 16);
    }
#pragma unroll 2
    for (int i = 0; i < QCH; ++i) {
        const int sn = s0 + ((i < QCH - 1) ? i + 1 : i);
        const int tn = d ? (LSEQ - 1 - sn) : sn;
        {
            const size_t rown = (size_t)b * LSEQ + tn, rdbn = (size_t)db * LSEQ + tn;
            xn  = b2f(xs[(dbase + rown) * DI + h * HP + lane]);
            dtn = dtb[rdbn * 32 + h]; dAn = dAb[rdbn * 32 + h];
            LD16V(Bn, Bc + rdbn * 16);
        }
        const float dtx = dtv * xv;
#pragma unroll
        for (int n = 0; n < 16; ++n) hs[n] = fmaf(hs[n], dAv, Bs[n] * dtx);
        pacc *= dAv;
        xv = xn; dtv = dtn; dAv = dAn;
#pragma unroll
        for (int n = 0; n < 16; ++n) Bs[n] = Bn[n];
    }
    float* Sp = Sbuf + (((size_t)(db * NH + h)) * NCH + c) * 1024 + lane * 16;
    ST16V(Sp, hs);
    if (lane == 0) Pbuf[(db * NH + h) * NCH + c] = pacc;
}

// ---------------- pass B: sequential combine over chunks (tiny) ----------------
__global__ __launch_bounds__(64) void chunk_combine_kernel(
    const float* __restrict__ Sbuf, const float* __restrict__ Pbuf,
    float* __restrict__ Hbuf)               // [128][NCH][64][16]
{
    const int idx = blockIdx.x;
    const int lane = threadIdx.x;
    float hs[16];
#pragma unroll
    for (int n = 0; n < 16; ++n) hs[n] = 0.f;
    float* H0 = Hbuf + ((size_t)idx * NCH) * 1024 + lane * 16;
    ST16V(H0, hs);
    for (int c = 0; c < NCH - 1; ++c) {
        const float* Sp = Sbuf + ((size_t)idx * NCH + c) * 1024 + lane * 16;
        float S[16];
        LD16V(S, Sp);
        const float P = Pbuf[idx * NCH + c];
#pragma unroll
        for (int n = 0; n < 16; ++n) hs[n] = fmaf(hs[n], P, S[n]);
        float* Hp = Hbuf + ((size_t)idx * NCH + c + 1) * 1024 + lane * 16;
        ST16V(Hp, hs);
    }
}

// ---------------- pass C: per-chunk scan from Hinit, emit y ----------------
__global__ __launch_bounds__(64) void chunk_scan_kernel(
    const unsigned short* __restrict__ xs,
    const float* __restrict__ Bc, const float* __restrict__ Cc,
    const float* __restrict__ dtb, const float* __restrict__ dAb,
    const float* __restrict__ DpF, const float* __restrict__ DpB,
    const float* __restrict__ Hbuf,
    unsigned short* __restrict__ ybuf)       // [2][4096][2048]
{
    const int h = blockIdx.x, db = blockIdx.y, c = blockIdx.z;
    const int d = db >> 1, b = db & 1;
    const int lane = threadIdx.x;
    const float Dp = (d ? DpB : DpF)[h];
    float hs[16];
    {
        const float* Hp = Hbuf + ((size_t)(db * NH + h) * NCH + c) * 1024 + lane * 16;
        LD16V(hs, Hp);
    }
    const size_t dbase = (size_t)d * RTOT;
    const int s0 = c * QCH;

    float Bs[16], Cs[16], xv, dtv, dAv;
    float Bn[16], Cn[16], xn, dtn, dAn;
    {
        const int t = d ? (LSEQ - 1 - s0) : s0;
        const size_t row = (size_t)b * LSEQ + t, rdb = (size_t)db * LSEQ + t;
        xv  = b2f(xs[(dbase + row) * DI + h * HP + lane]);
        dtv = dtb[rdb * 32 + h]; dAv = dAb[rdb * 32 + h];
        LD16V(Bs, Bc + rdb * 16);
        LD16V(Cs, Cc + rdb * 16);
    }
#pragma unroll 2
    for (int i = 0; i < QCH; ++i) {
        const int sn = s0 + ((i < QCH - 1) ? i + 1 : i);
        const int tn = d ? (LSEQ - 1 - sn) : sn;
        {
            const size_t rown = (size_t)b * LSEQ + tn, rdbn = (size_t)db * LSEQ + tn;
            xn  = b2f(xs[(dbase + rown) * DI + h * HP + lane]);
            dtn = dtb[rdbn * 32 + h]; dAn = dAb[rdbn * 32 + h];
            LD16V(Bn, Bc + rdbn * 16);
            LD16V(Cn, Cc + rdbn * 16);
        }
        const float dtx = dtv * xv;
        float yq[4] = {0.f, 0.f, 0.f, 0.f};
#pragma unroll
        for (int n = 0; n < 16; ++n) {
            hs[n] = fmaf(hs[n], dAv, Bs[n] * dtx);
            yq[n & 3] = fmaf(Cs[n], hs[n], yq[n & 3]);
        }
        const int t = d ? (LSEQ - 1 - (s0 + i)) : (s0 + i);
        const size_t row = (size_t)b * LSEQ + t;
        ybuf[(dbase + row) * DI + h * HP + lane] = f2b(((yq[0] + yq[1]) + (yq[2] + yq[3])) + Dp * xv);

        xv = xn; dtv = dtn; dAv = dAn;
#pragma unroll
        for (int n = 0; n < 16; ++n) { Bs[n] = Bn[n]; Cs[n] = Cn[n]; }
    }
}

// ---------------- gate (silu(z)) + RMSNorm -> bf16 ----------------
__global__ __launch_bounds__(256) void gatenorm_kernel(
    const unsigned short* __restrict__ ybuf, const unsigned short* __restrict__ ZX,
    const float* __restrict__ nwF, const float* __restrict__ nwB,
    unsigned short* __restrict__ yg)
{
    const int r = blockIdx.x;      // 0..4095 (b*L+t)
    const int d = blockIdx.y;
    const int tid = threadIdx.x;
    const float* nw = d ? nwB : nwF;
    const int c0 = tid * 8;
    const unsigned short* yp = ybuf + ((size_t)d * RTOT + r) * DI + c0;
    const unsigned short* zp = ZX + (size_t)r * NW + d * DIP + c0;
    uint4 yv = *(const uint4*)yp;
    uint4 zv = *(const uint4*)zp;
    unsigned int yw[4] = {yv.x, yv.y, yv.z, yv.w};
    unsigned int zw[4] = {zv.x, zv.y, zv.z, zv.w};
    float g[8]; float ss = 0.f;
#pragma unroll
    for (int i = 0; i < 8; ++i) {
        unsigned short yu = (i & 1) ? (unsigned short)(yw[i >> 1] >> 16) : (unsigned short)(yw[i >> 1] & 0xffff);
        unsigned short zu = (i & 1) ? (unsigned short)(zw[i >> 1] >> 16) : (unsigned short)(zw[i >> 1] & 0xffff);
        float y = b2f(yu), z = b2f(zu);
        float gv = y * silu_f(z);
        g[i] = gv; ss += gv * gv;
    }
#pragma unroll
    for (int m = 1; m < 64; m <<= 1) ss += __shfl_xor(ss, m, 64);
    __shared__ float red[4];
    if ((tid & 63) == 0) red[tid >> 6] = ss;
    __syncthreads();
    float tot = red[0] + red[1] + red[2] + red[3];
    float sc = rsqrtf(tot * (1.f / 2048.f) + 1e-5f);
    union { unsigned short s[8]; uint4 u; } o;
#pragma unroll
    for (int i = 0; i < 8; ++i) o.s[i] = f2b(g[i] * sc * nw[c0 + i]);
    *(uint4*)(yg + ((size_t)d * RTOT + r) * DI + c0) = o.u;
}

// ---------------- host ----------------
extern "C" void kernel_launch(void* const* d_in, const int* in_sizes, int n_in,
                              void* d_out, int out_size, void* d_ws, size_t ws_size,
                              hipStream_t stream)
{
    const float* x     = (const float*)d_in[0];
    const float* fin   = (const float*)d_in[1];
    const float* fcw   = (const float*)d_in[2];
    const float* fcb   = (const float*)d_in[3];
    const float* fdtb  = (const float*)d_in[4];
    const float* fAlog = (const float*)d_in[5];
    const float* fDp   = (const float*)d_in[6];
    const float* fnw   = (const float*)d_in[7];
    const float* fout  = (const float*)d_in[8];
    const float* bin   = (const float*)d_in[9];
    const float* bcw   = (const float*)d_in[10];
    const float* bcb   = (const float*)d_in[11];
    const float* bdtb  = (const float*)d_in[12];
    const float* bAlog = (const float*)d_in[13];
    const float* bDp   = (const float*)d_in[14];
    const float* bnw   = (const float*)d_in[15];
    const float* bout  = (const float*)d_in[16];
    const float* lw    = (const float*)d_in[17];
    const float* lsc   = (const float*)d_in[18];

    char* w = (char*)d_ws;
    auto alloc = [&](size_t bytes) { char* p = w; w += (bytes + 255) & ~(size_t)255; return p; };
    unsigned short* xb  = (unsigned short*)alloc((size_t)RTOT * DM * 2);
    unsigned short* win = (unsigned short*)alloc((size_t)NW * DM * 2);
    unsigned short* wo  = (unsigned short*)alloc((size_t)2 * DM * DI * 2);
    unsigned short* wl  = (unsigned short*)alloc((size_t)DM * DI * 2);
    unsigned short* zx  = (unsigned short*)alloc((size_t)RTOT * NW * 2);
    unsigned short* xs  = (unsigned short*)alloc((size_t)2 * RTOT * DI * 2);
    float* Bc  = (float*)alloc((size_t)2 * RTOT * NSTATE * 4);
    float* Cc  = (float*)alloc((size_t)2 * RTOT * NSTATE * 4);
    float* dtb = (float*)alloc((size_t)2 * RTOT * NH * 4);
    float* dAb = (float*)alloc((size_t)2 * RTOT * NH * 4);
    unsigned short* yb  = (unsigned short*)alloc((size_t)2 * RTOT * DI * 2);
    unsigned short* yg  = (unsigned short*)alloc((size_t)2 * RTOT * DI * 2);
    unsigned short* hbi = (unsigned short*)alloc((size_t)RTOT * DI * 2);
    float* Pbuf = (float*)alloc((size_t)128 * NCH * 4);
    // Sbuf/Hbuf alias xb and win (dead after GEMM A).
    float* Sbuf = (float*)xb;
    float* Hbuf = (float*)win;
    (void)ws_size; (void)in_sizes; (void)n_in; (void)out_size;

    // batched weight/activation converts to bf16 (one dispatch)
    CvtJobs jobs;
    jobs.src[0] = x;    jobs.dst[0] = xb;                        jobs.n4[0] = RTOT * DM / 4;
    jobs.src[1] = fin;  jobs.dst[1] = win;                       jobs.n4[1] = DIP * DM / 4;
    jobs.src[2] = bin;  jobs.dst[2] = win + (size_t)DIP * DM;    jobs.n4[2] = DIP * DM / 4;
    jobs.src[3] = fout; jobs.dst[3] = wo;                        jobs.n4[3] = DM * DI / 4;
    jobs.src[4] = bout; jobs.dst[4] = wo + (size_t)DM * DI;      jobs.n4[4] = DM * DI / 4;
    jobs.src[5] = lw;   jobs.dst[5] = wl;                        jobs.n4[5] = DM * DI / 4;
    cvtb_kernel<<<dim3((DIP * DM / 4 + 255) / 256, 6), 256, 0, stream>>>(jobs);

    // GEMM A: zxbcdt for both dirs (stacked weights)  M=4096,N=8320,K=1024
    gemm3_kernel<1><<<dim3(NW / 128, RTOT / 256), 512, 0, stream>>>(
        xb, win, nullptr, nullptr, zx, DM, NW, 0, 0, nullptr, nullptr);

    // conv + silu + split (fwd causal, bwd anti-causal), sliding-window
    conv_kernel<<<dim3((CDIM + 255) / 256, LSEQ / TCV, 4), 256, 0, stream>>>(
        zx, fcw, fcb, bcw, bcb, xs, Bc, Cc);

    // dt softplus + dA
    dt_kernel<<<(2 * NB * LSEQ * NH) / 256, 256, 0, stream>>>(
        zx, fdtb, fAlog, bdtb, bAlog, dtb, dAb);

    // chunked scan: A) per-chunk states, B) combine, C) per-chunk scan+y
    chunk_state_kernel<<<dim3(NH, 4, NCH - 1), 64, 0, stream>>>(
        xs, Bc, dtb, dAb, Sbuf, Pbuf);
    chunk_combine_kernel<<<128, 64, 0, stream>>>(Sbuf, Pbuf, Hbuf);
    chunk_scan_kernel<<<dim3(NH, 4, NCH), 64, 0, stream>>>(
        xs, Bc, Cc, dtb, dAb, fDp, bDp, Hbuf, yb);

    // gate + RMSNorm
    gatenorm_kernel<<<dim3(RTOT, 2), 256, 0, stream>>>(yb, zx, fnw, bnw, yg);

    // GEMM B: out_proj both dirs fused in one dispatch (grid.z=2)  M=4096,N=1024,K=2048
    gemm3_kernel<1><<<dim3(DM / 128, RTOT / 256, 2), 512, 0, stream>>>(
        yg, wo, yg + (size_t)RTOT * DI, wo + (size_t)DM * DI,
        hbi, DI, DI, 0, DM, nullptr, nullptr);

    // GEMM C: layer out proj + residual epilogue  M=4096,N=1024,K=2048
    gemm3_kernel<2><<<dim3(DM / 128, RTOT / 256), 512, 0, stream>>>(
        hbi, wl, nullptr, nullptr, d_out, DI, DM, 0, 0, x, lsc);
}